// Round 2
// baseline (546.912 us; speedup 1.0000x reference)
//
#include <hip/hip_runtime.h>
#include <stdint.h>

#define LL 512
#define DD 64

typedef __attribute__((ext_vector_type(8))) short bf16x8;
typedef __attribute__((ext_vector_type(4))) float f32x4;

#define MFMA16(a, b, c) __builtin_amdgcn_mfma_f32_16x16x32_bf16((a), (b), (c), 0, 0, 0)

__device__ __forceinline__ float bf2f(unsigned short u) {
    union { unsigned int i; float f; } v; v.i = ((unsigned int)u) << 16; return v.f;
}
__device__ __forceinline__ unsigned short f2bf(float f) {
    union { float f; unsigned int i; } v; v.f = f;
    unsigned int i = v.i;
    return (unsigned short)((i + 0x7FFFu + ((i >> 16) & 1u)) >> 16);  // RNE
}
__device__ __forceinline__ float sigm(float x) { return 1.0f / (1.0f + __expf(-x)); }

// ---------------------------------------------------------------- prep ------
__global__ void prep_w(const float* __restrict__ Wl, const float* __restrict__ Wr,
                       const float* __restrict__ Wlg, const float* __restrict__ Wrg,
                       const float* __restrict__ Wog, const float* __restrict__ Wout,
                       unsigned short* __restrict__ Wcat, unsigned short* __restrict__ WoutB) {
    int t = threadIdx.x + blockIdx.x * blockDim.x;
    int stride = blockDim.x * gridDim.x;
    for (int idx = t; idx < 320 * 64; idx += stride) {
        int row = idx >> 6, col = idx & 63;
        int sec = row >> 6, r = row & 63;
        float v;
        switch (sec) {
            case 0:  v = Wl[r * 64 + col];  break;
            case 1:  v = Wlg[r * 64 + col]; break;
            case 2:  v = Wr[r * 64 + col];  break;
            case 3:  v = Wrg[r * 64 + col]; break;
            default: v = Wog[r * 64 + col]; break;
        }
        Wcat[idx] = f2bf(v);
    }
    for (int idx = t; idx < 64 * 64; idx += stride) WoutB[idx] = f2bf(Wout[idx]);
}

// ------------------------------------------------- k1: LN + proj + gates ----
// block: (b, irow, 128-chunk of second index). 256 threads = 4 waves.
// All global writes are LDS-staged and fully coalesced (round-2 fix: the
// round-1 version scattered 8B stores across 512KB-apart planes -> latency
// bound at 323us with MfmaUtil 2.7% / VALUBusy 26%).
__launch_bounds__(256)
__global__ void k1_proj(const float* __restrict__ pair, const float* __restrict__ torsion,
                        const float* __restrict__ ln_g, const float* __restrict__ ln_b,
                        const float* __restrict__ blg, const float* __restrict__ brg,
                        const float* __restrict__ bog, const float* __restrict__ Wt,
                        const float* __restrict__ bt, const unsigned short* __restrict__ Wcat,
                        unsigned short* __restrict__ At, unsigned short* __restrict__ Bt,
                        unsigned short* __restrict__ G) {
    const int bb = blockIdx.z, irow = blockIdx.y, c0 = blockIdx.x * 128;
    const int t = threadIdx.x, w = t >> 6, lane = t & 63;
    __shared__ unsigned short zs[128][72];    // z bf16 [pos][d]; reused in-place for G
    __shared__ unsigned short awL[64][132];   // aw d-major [d][pos], pitch 264B
    __shared__ unsigned short bL[64][132];    // b  d-major [d][pos]

    float tww;
    {
        float acc = bt[0];
        #pragma unroll
        for (int n = 0; n < 6; ++n) acc += torsion[(bb * LL + irow) * 6 + n] * Wt[n];
        tww = sigm(acc);
    }

    const float lg = ln_g[lane], lb = ln_b[lane];
    const float* prow = pair + ((size_t)(bb * LL + irow) * LL + c0) * DD;
    for (int r = w; r < 128; r += 4) {
        float v = prow[r * DD + lane];
        float s = v, s2 = v * v;
        #pragma unroll
        for (int off = 32; off > 0; off >>= 1) {
            s += __shfl_xor(s, off);
            s2 += __shfl_xor(s2, off);
        }
        float m = s * 0.015625f;
        float var = s2 * 0.015625f - m * m;
        float rstd = rsqrtf(var + 1e-5f);
        zs[r][lane] = f2bf((v - m) * rstd * lg + lb);
    }
    __syncthreads();

    const int rsel = lane & 15, koff = lane >> 4;
    // mh MUST stay the outer loop: each wave reads its a-fragments for rows
    // [mi*16, mi*16+16) before the n-loop overwrites exactly those zs rows
    // with G values (zs is [pos][d] == G layout). Rows are wave-private.
    #pragma unroll
    for (int mh = 0; mh < 2; ++mh) {
        const int mi = 2 * w + mh;
        bf16x8 a0 = *(const bf16x8*)&zs[mi * 16 + rsel][koff * 8];
        bf16x8 a1 = *(const bf16x8*)&zs[mi * 16 + rsel][32 + koff * 8];
        #pragma unroll
        for (int n = 0; n < 4; ++n) {
            const int col = n * 16 + rsel;   // output channel d
            f32x4 pl = {0.f, 0.f, 0.f, 0.f}, plg = pl, pr = pl, prg = pl, pog = pl;
            const unsigned short* w0 = Wcat + (size_t)(0 * 64 + col) * 64;
            const unsigned short* w1 = Wcat + (size_t)(1 * 64 + col) * 64;
            const unsigned short* w2 = Wcat + (size_t)(2 * 64 + col) * 64;
            const unsigned short* w3 = Wcat + (size_t)(3 * 64 + col) * 64;
            const unsigned short* w4 = Wcat + (size_t)(4 * 64 + col) * 64;
            pl  = MFMA16(a0, *(const bf16x8*)&w0[koff * 8], pl);
            pl  = MFMA16(a1, *(const bf16x8*)&w0[32 + koff * 8], pl);
            plg = MFMA16(a0, *(const bf16x8*)&w1[koff * 8], plg);
            plg = MFMA16(a1, *(const bf16x8*)&w1[32 + koff * 8], plg);
            pr  = MFMA16(a0, *(const bf16x8*)&w2[koff * 8], pr);
            pr  = MFMA16(a1, *(const bf16x8*)&w2[32 + koff * 8], pr);
            prg = MFMA16(a0, *(const bf16x8*)&w3[koff * 8], prg);
            prg = MFMA16(a1, *(const bf16x8*)&w3[32 + koff * 8], prg);
            pog = MFMA16(a0, *(const bf16x8*)&w4[koff * 8], pog);
            pog = MFMA16(a1, *(const bf16x8*)&w4[32 + koff * 8], pog);

            const float vblg = blg[col], vbrg = brg[col], vbog = bog[col];
            const int crow = mi * 16 + koff * 4;   // 4 consecutive positions
            unsigned short aw4[4], bm4[4];
            #pragma unroll
            for (int r = 0; r < 4; ++r) {
                float av = pl[r] * sigm(plg[r] + vblg) * tww;
                float bv = pr[r] * sigm(prg[r] + vbrg);
                float gv = sigm(pog[r] + vbog);
                aw4[r] = f2bf(av); bm4[r] = f2bf(bv);
                zs[crow + r][col] = f2bf(gv);      // G in-place, [pos][d]
            }
            *(ushort4*)&awL[col][crow] = make_ushort4(aw4[0], aw4[1], aw4[2], aw4[3]);
            *(ushort4*)&bL[col][crow]  = make_ushort4(bm4[0], bm4[1], bm4[2], bm4[3]);
        }
    }
    __syncthreads();

    // Coalesced write-out: At/Bt as 64 contiguous 256B chunks each.
    #pragma unroll
    for (int it = 0; it < 8; ++it) {
        int d = it * 8 + (t >> 5);
        int c8 = (t & 31) * 4;
        size_t base = ((size_t)(bb * 64 + d) * LL + irow) * LL + c0 + c8;
        *(ushort4*)&At[base] = *(const ushort4*)&awL[d][c8];
        *(ushort4*)&Bt[base] = *(const ushort4*)&bL[d][c8];
    }
    // G: one contiguous 16KB block, [pos][d].
    #pragma unroll
    for (int it = 0; it < 8; ++it) {
        int r = it * 16 + (t >> 4), cc = (t & 15) * 4;
        size_t pos = (size_t)(bb * LL + irow) * LL + c0 + r;
        *(ushort4*)&G[pos * DD + cc] = *(const ushort4*)&zs[r][cc];
    }
}

// ------------------------------------------ k2: batched plane GEMM (AB^T) ---
// grid: x = 16 tiles (4x4 of 128x128), y = 128 planes. 256 threads = 4 waves.
__launch_bounds__(256)
__global__ void k2_gemm(const unsigned short* __restrict__ At,
                        const unsigned short* __restrict__ Bt,
                        unsigned short* __restrict__ Xt) {
    const int p = blockIdx.y;
    const int i0 = (blockIdx.x >> 2) * 128, j0 = (blockIdx.x & 3) * 128;
    const unsigned short* Ap = At + (size_t)p * LL * LL + (size_t)i0 * LL;
    const unsigned short* Bp = Bt + (size_t)p * LL * LL + (size_t)j0 * LL;
    __shared__ unsigned short As[128][40], Bs[128][40];   // pitch 80B (16B-aligned, ~2-way banks)
    __shared__ unsigned short Cs[128][136];               // pitch 272B (16B-aligned)
    const int t = threadIdx.x, lane = t & 63, w = t >> 6;
    const int rsel = lane & 15, koff = lane >> 4;
    const int wm = w >> 1, wn = w & 1;

    f32x4 acc[4][4];
    #pragma unroll
    for (int i = 0; i < 4; ++i)
        #pragma unroll
        for (int j = 0; j < 4; ++j) acc[i][j] = (f32x4){0.f, 0.f, 0.f, 0.f};

    const int srow0 = t >> 2, skq = t & 3;
    uint4 ra[2], rb[2];
    #pragma unroll
    for (int q = 0; q < 2; ++q) {
        int row = srow0 + q * 64;
        ra[q] = *(const uint4*)&Ap[(size_t)row * LL + skq * 8];
        rb[q] = *(const uint4*)&Bp[(size_t)row * LL + skq * 8];
    }
    for (int k0 = 0; k0 < LL; k0 += 32) {
        #pragma unroll
        for (int q = 0; q < 2; ++q) {
            int row = srow0 + q * 64;
            *(uint4*)&As[row][skq * 8] = ra[q];
            *(uint4*)&Bs[row][skq * 8] = rb[q];
        }
        __syncthreads();
        if (k0 + 32 < LL) {
            #pragma unroll
            for (int q = 0; q < 2; ++q) {
                int row = srow0 + q * 64;
                ra[q] = *(const uint4*)&Ap[(size_t)row * LL + (k0 + 32) + skq * 8];
                rb[q] = *(const uint4*)&Bp[(size_t)row * LL + (k0 + 32) + skq * 8];
            }
        }
        bf16x8 af[4], bfr[4];
        #pragma unroll
        for (int mi = 0; mi < 4; ++mi)
            af[mi] = *(const bf16x8*)&As[wm * 64 + mi * 16 + rsel][koff * 8];
        #pragma unroll
        for (int ni = 0; ni < 4; ++ni)
            bfr[ni] = *(const bf16x8*)&Bs[wn * 64 + ni * 16 + rsel][koff * 8];
        #pragma unroll
        for (int mi = 0; mi < 4; ++mi)
            #pragma unroll
            for (int ni = 0; ni < 4; ++ni)
                acc[mi][ni] = MFMA16(af[mi], bfr[ni], acc[mi][ni]);
        __syncthreads();
    }
    const float s = 1.0f / (sqrtf((float)LL) + 1e-8f);
    #pragma unroll
    for (int mi = 0; mi < 4; ++mi)
        #pragma unroll
        for (int ni = 0; ni < 4; ++ni)
            #pragma unroll
            for (int r = 0; r < 4; ++r)
                Cs[wm * 64 + mi * 16 + koff * 4 + r][wn * 64 + ni * 16 + rsel] =
                    f2bf(acc[mi][ni][r] * s);
    __syncthreads();
    #pragma unroll
    for (int it = 0; it < 8; ++it) {
        int row = it * 16 + (t >> 4), colc = (t & 15) * 8;
        uint4 v = *(const uint4*)&Cs[row][colc];
        *(uint4*)&Xt[((size_t)p * LL + i0 + row) * LL + j0 + colc] = v;
    }
}

// ----------------------------- k3: transpose + LN + out-proj + gate + res ---
__launch_bounds__(256)
__global__ void k3_out(const unsigned short* __restrict__ Xt, const unsigned short* __restrict__ G,
                       const float* __restrict__ pairIn, const unsigned short* __restrict__ WoutB,
                       const float* __restrict__ lno_g, const float* __restrict__ lno_b,
                       const float* __restrict__ bout, float* __restrict__ out) {
    const int bb = blockIdx.z, irow = blockIdx.y, c0 = blockIdx.x * 128;
    const int t = threadIdx.x, w = t >> 6, lane = t & 63;
    __shared__ unsigned short x1[64][128];   // [d][c] staging, reused as o_lds [128][64]
    __shared__ unsigned short x2[128][72];   // [c][d] transposed

    #pragma unroll
    for (int q = 0; q < 4; ++q) {
        int idx = t + q * 256, d = idx >> 4, c8 = idx & 15;
        uint4 v = *(const uint4*)&Xt[((size_t)(bb * 64 + d) * LL + irow) * LL + c0 + c8 * 8];
        *(uint4*)&x1[d][c8 * 8] = v;
    }
    __syncthreads();
    {
        const int c = t & 127, half = t >> 7;
        unsigned short tmp[32];
        #pragma unroll
        for (int dd = 0; dd < 32; ++dd) tmp[dd] = x1[half * 32 + dd][c];
        #pragma unroll
        for (int q = 0; q < 4; ++q)
            *(uint4*)&x2[c][half * 32 + q * 8] = *(const uint4*)&tmp[q * 8];
    }
    __syncthreads();

    const float lg = lno_g[lane], lb = lno_b[lane];
    for (int r = w; r < 128; r += 4) {
        float v = bf2f(x2[r][lane]);
        float s = v, s2 = v * v;
        #pragma unroll
        for (int off = 32; off > 0; off >>= 1) {
            s += __shfl_xor(s, off);
            s2 += __shfl_xor(s2, off);
        }
        float m = s * 0.015625f;
        float var = s2 * 0.015625f - m * m;
        float rstd = rsqrtf(var + 1e-5f);
        x2[r][lane] = f2bf((v - m) * rstd * lg + lb);
    }
    __syncthreads();

    unsigned short* o_lds = &x1[0][0];   // [128][64]
    const int rsel = lane & 15, koff = lane >> 4;
    #pragma unroll
    for (int mh = 0; mh < 2; ++mh) {
        const int mi = 2 * w + mh;
        bf16x8 a0 = *(const bf16x8*)&x2[mi * 16 + rsel][koff * 8];
        bf16x8 a1 = *(const bf16x8*)&x2[mi * 16 + rsel][32 + koff * 8];
        #pragma unroll
        for (int n = 0; n < 4; ++n) {
            f32x4 pacc = {0.f, 0.f, 0.f, 0.f};
            const unsigned short* wrow = WoutB + (size_t)(n * 16 + rsel) * 64;
            pacc = MFMA16(a0, *(const bf16x8*)&wrow[koff * 8], pacc);
            pacc = MFMA16(a1, *(const bf16x8*)&wrow[32 + koff * 8], pacc);
            const float bo = bout[n * 16 + rsel];
            #pragma unroll
            for (int r = 0; r < 4; ++r)
                o_lds[(mi * 16 + koff * 4 + r) * 64 + n * 16 + rsel] = f2bf(pacc[r] + bo);
        }
    }
    __syncthreads();

    #pragma unroll
    for (int q = 0; q < 4; ++q) {
        int e = q * 2048 + t * 8;
        int c = e >> 6, o = e & 63;
        size_t pos = (size_t)(bb * LL + irow) * LL + c0 + c;
        uint4 ov = *(const uint4*)&o_lds[c * 64 + o];
        uint4 gv = *(const uint4*)&G[pos * DD + o];
        const unsigned short* ovp = (const unsigned short*)&ov;
        const unsigned short* gvp = (const unsigned short*)&gv;
        float4 p0 = *(const float4*)&pairIn[pos * DD + o];
        float4 p1 = *(const float4*)&pairIn[pos * DD + o + 4];
        float4 r0, r1;
        r0.x = p0.x + bf2f(ovp[0]) * bf2f(gvp[0]);
        r0.y = p0.y + bf2f(ovp[1]) * bf2f(gvp[1]);
        r0.z = p0.z + bf2f(ovp[2]) * bf2f(gvp[2]);
        r0.w = p0.w + bf2f(ovp[3]) * bf2f(gvp[3]);
        r1.x = p1.x + bf2f(ovp[4]) * bf2f(gvp[4]);
        r1.y = p1.y + bf2f(ovp[5]) * bf2f(gvp[5]);
        r1.z = p1.z + bf2f(ovp[6]) * bf2f(gvp[6]);
        r1.w = p1.w + bf2f(ovp[7]) * bf2f(gvp[7]);
        *(float4*)&out[pos * DD + o] = r0;
        *(float4*)&out[pos * DD + o + 4] = r1;
    }
}

// ----------------------------------------------------------------- launch ---
extern "C" void kernel_launch(void* const* d_in, const int* in_sizes, int n_in,
                              void* d_out, int out_size, void* d_ws, size_t ws_size,
                              hipStream_t stream) {
    const float* pair    = (const float*)d_in[0];
    const float* torsion = (const float*)d_in[1];
    const float* ln_g    = (const float*)d_in[2];
    const float* ln_b    = (const float*)d_in[3];
    const float* Wl      = (const float*)d_in[4];
    const float* Wr      = (const float*)d_in[5];
    const float* Wlg     = (const float*)d_in[6];
    const float* blg     = (const float*)d_in[7];
    const float* Wrg     = (const float*)d_in[8];
    const float* brg     = (const float*)d_in[9];
    const float* Wog     = (const float*)d_in[10];
    const float* bog     = (const float*)d_in[11];
    const float* Wout    = (const float*)d_in[12];
    const float* bout    = (const float*)d_in[13];
    const float* lno_g   = (const float*)d_in[14];
    const float* lno_b   = (const float*)d_in[15];
    const float* Wt      = (const float*)d_in[16];
    const float* bt      = (const float*)d_in[17];
    float* outp = (float*)d_out;

    const size_t PLANE_B = (size_t)128 * LL * LL * 2;   // 64 MiB per block
    const size_t need = 4 * PLANE_B + (320 * 64 + 64 * 64) * 2;
    if (ws_size < need) return;   // insufficient workspace; fail validation cleanly

    char* ws = (char*)d_ws;
    unsigned short* At    = (unsigned short*)(ws);
    unsigned short* Bt_   = (unsigned short*)(ws + PLANE_B);
    unsigned short* G     = (unsigned short*)(ws + 2 * PLANE_B);
    unsigned short* Xt    = (unsigned short*)(ws + 3 * PLANE_B);
    unsigned short* Wcat  = (unsigned short*)(ws + 4 * PLANE_B);
    unsigned short* WoutB = Wcat + 320 * 64;

    prep_w<<<dim3(40), dim3(256), 0, stream>>>(Wl, Wr, Wlg, Wrg, Wog, Wout, Wcat, WoutB);
    k1_proj<<<dim3(4, LL, 2), dim3(256), 0, stream>>>(pair, torsion, ln_g, ln_b, blg, brg,
                                                      bog, Wt, bt, Wcat, At, Bt_, G);
    k2_gemm<<<dim3(16, 128), dim3(256), 0, stream>>>(At, Bt_, Xt);
    k3_out<<<dim3(4, LL, 2), dim3(256), 0, stream>>>(Xt, G, pair, WoutB, lno_g, lno_b, bout, outp);
}

// Round 4
// 445.823 us; speedup vs baseline: 1.2267x; 1.2267x over previous
//
#include <hip/hip_runtime.h>
#include <stdint.h>

#define LL 512
#define DD 64

typedef __attribute__((ext_vector_type(8))) short bf16x8;
typedef __attribute__((ext_vector_type(4))) float f32x4;

#define MFMA16(a, b, c) __builtin_amdgcn_mfma_f32_16x16x32_bf16((a), (b), (c), 0, 0, 0)

__device__ __forceinline__ float bf2f(unsigned short u) {
    union { unsigned int i; float f; } v; v.i = ((unsigned int)u) << 16; return v.f;
}
__device__ __forceinline__ unsigned short f2bf(float f) {
    union { float f; unsigned int i; } v; v.f = f;
    unsigned int i = v.i;
    return (unsigned short)((i + 0x7FFFu + ((i >> 16) & 1u)) >> 16);  // RNE
}
// NOTE round-3 lesson: __builtin_amdgcn_rcpf here pushed absmax 0.031->0.203
// (> threshold). Keep the exact division.
__device__ __forceinline__ float sigm(float x) { return 1.0f / (1.0f + __expf(-x)); }

// ---------------------------------------------------------------- prep ------
__global__ void prep_w(const float* __restrict__ Wl, const float* __restrict__ Wr,
                       const float* __restrict__ Wlg, const float* __restrict__ Wrg,
                       const float* __restrict__ Wog, const float* __restrict__ Wout,
                       unsigned short* __restrict__ Wcat, unsigned short* __restrict__ WoutB) {
    int t = threadIdx.x + blockIdx.x * blockDim.x;
    int stride = blockDim.x * gridDim.x;
    for (int idx = t; idx < 320 * 64; idx += stride) {
        int row = idx >> 6, col = idx & 63;
        int sec = row >> 6, r = row & 63;
        float v;
        switch (sec) {
            case 0:  v = Wl[r * 64 + col];  break;
            case 1:  v = Wlg[r * 64 + col]; break;
            case 2:  v = Wr[r * 64 + col];  break;
            case 3:  v = Wrg[r * 64 + col]; break;
            default: v = Wog[r * 64 + col]; break;
        }
        Wcat[idx] = f2bf(v);
    }
    for (int idx = t; idx < 64 * 64; idx += stride) WoutB[idx] = f2bf(Wout[idx]);
}

// ------------------------------------------------- k1: LN + proj + gates ----
// Structure: wave w owns output-channel group (cols w*16..w*16+15) for ALL 8
// position tiles; the 10 weight fragments live in registers (loaded once,
// reused 8x) instead of per-tile scattered L2 gathers.
// Numerics: exact-div sigmoid + round-2 LN reduction (both validated).
__launch_bounds__(256)
__global__ void k1_proj(const float* __restrict__ pair, const float* __restrict__ torsion,
                        const float* __restrict__ ln_g, const float* __restrict__ ln_b,
                        const float* __restrict__ blg, const float* __restrict__ brg,
                        const float* __restrict__ bog, const float* __restrict__ Wt,
                        const float* __restrict__ bt, const unsigned short* __restrict__ Wcat,
                        unsigned short* __restrict__ At, unsigned short* __restrict__ Bt,
                        unsigned short* __restrict__ G) {
    const int bb = blockIdx.z, irow = blockIdx.y, c0 = blockIdx.x * 128;
    const int t = threadIdx.x, w = t >> 6, lane = t & 63;
    const int rsel = lane & 15, koff = lane >> 4;
    const int col = w * 16 + rsel;            // this wave's output channel
    __shared__ unsigned short zs[128][72];    // z bf16 [pos][d]; later reused for G
    __shared__ unsigned short awL[64][132];   // aw d-major [d][pos]
    __shared__ unsigned short bL[64][132];    // b  d-major [d][pos]

    float tww;
    {
        float acc = bt[0];
        #pragma unroll
        for (int n = 0; n < 6; ++n) acc += torsion[(bb * LL + irow) * 6 + n] * Wt[n];
        tww = sigm(acc);
    }

    // Hoisted weight fragments: 5 matrices x 2 k-halves, 16B each (40 VGPR).
    bf16x8 wfr[5][2];
    #pragma unroll
    for (int s = 0; s < 5; ++s)
        #pragma unroll
        for (int kh = 0; kh < 2; ++kh)
            wfr[s][kh] = *(const bf16x8*)&Wcat[(size_t)(s * 64 + col) * 64 + kh * 32 + koff * 8];
    const float vblg = blg[col], vbrg = brg[col], vbog = bog[col];

    // ---- LN (round-2 proven form): one row per wave pass, lane = d ----
    const float lg = ln_g[lane], lb = ln_b[lane];
    const float* prow = pair + ((size_t)(bb * LL + irow) * LL + c0) * DD;
    for (int r = w; r < 128; r += 4) {
        float v = prow[r * DD + lane];
        float s = v, s2 = v * v;
        #pragma unroll
        for (int off = 32; off > 0; off >>= 1) {
            s += __shfl_xor(s, off);
            s2 += __shfl_xor(s2, off);
        }
        float m = s * 0.015625f;
        float var = s2 * 0.015625f - m * m;
        float rstd = rsqrtf(var + 1e-5f);
        zs[r][lane] = f2bf((v - m) * rstd * lg + lb);
    }
    __syncthreads();

    // ---- projections: 8 position tiles, weights stay in registers ----
    ushort4 gk[8];
    #pragma unroll
    for (int mi = 0; mi < 8; ++mi) {
        bf16x8 a0 = *(const bf16x8*)&zs[mi * 16 + rsel][koff * 8];
        bf16x8 a1 = *(const bf16x8*)&zs[mi * 16 + rsel][32 + koff * 8];
        f32x4 pl = {0.f, 0.f, 0.f, 0.f}, plg = pl, pr = pl, prg = pl, pog = pl;
        pl  = MFMA16(a0, wfr[0][0], pl);  pl  = MFMA16(a1, wfr[0][1], pl);
        plg = MFMA16(a0, wfr[1][0], plg); plg = MFMA16(a1, wfr[1][1], plg);
        pr  = MFMA16(a0, wfr[2][0], pr);  pr  = MFMA16(a1, wfr[2][1], pr);
        prg = MFMA16(a0, wfr[3][0], prg); prg = MFMA16(a1, wfr[3][1], prg);
        pog = MFMA16(a0, wfr[4][0], pog); pog = MFMA16(a1, wfr[4][1], pog);

        const int crow = mi * 16 + koff * 4;
        unsigned short aw4[4], bm4[4], g4[4];
        #pragma unroll
        for (int r = 0; r < 4; ++r) {
            float av = pl[r] * sigm(plg[r] + vblg) * tww;
            float bv = pr[r] * sigm(prg[r] + vbrg);
            float gv = sigm(pog[r] + vbog);
            aw4[r] = f2bf(av); bm4[r] = f2bf(bv); g4[r] = f2bf(gv);
        }
        *(ushort4*)&awL[col][crow] = make_ushort4(aw4[0], aw4[1], aw4[2], aw4[3]);
        *(ushort4*)&bL[col][crow]  = make_ushort4(bm4[0], bm4[1], bm4[2], bm4[3]);
        gk[mi] = make_ushort4(g4[0], g4[1], g4[2], g4[3]);
    }
    __syncthreads();   // all waves done reading z from zs

    // Dump gate regs into zs (wave-private cells), [pos][d] == G layout.
    #pragma unroll
    for (int mi = 0; mi < 8; ++mi) {
        const int rbase = mi * 16 + koff * 4;
        zs[rbase + 0][col] = gk[mi].x;
        zs[rbase + 1][col] = gk[mi].y;
        zs[rbase + 2][col] = gk[mi].z;
        zs[rbase + 3][col] = gk[mi].w;
    }
    __syncthreads();

    // Coalesced write-out: At/Bt as contiguous 256B chunks per d-row.
    #pragma unroll
    for (int it = 0; it < 8; ++it) {
        int d = it * 8 + (t >> 5);
        int c8 = (t & 31) * 4;
        size_t base = ((size_t)(bb * 64 + d) * LL + irow) * LL + c0 + c8;
        *(ushort4*)&At[base] = *(const ushort4*)&awL[d][c8];
        *(ushort4*)&Bt[base] = *(const ushort4*)&bL[d][c8];
    }
    // G: one contiguous 16KB block, [pos][d].
    #pragma unroll
    for (int it = 0; it < 8; ++it) {
        int r = it * 16 + (t >> 4), cc = (t & 15) * 4;
        size_t pos = (size_t)(bb * LL + irow) * LL + c0 + r;
        *(ushort4*)&G[pos * DD + cc] = *(const ushort4*)&zs[r][cc];
    }
}

// ------------------------------------------ k2: batched plane GEMM (AB^T) ---
// grid: x = 16 tiles (4x4 of 128x128), y = 128 planes. 256 threads = 4 waves.
// XCD-chunked bijective swizzle (2048 % 8 == 0) for L2 panel reuse.
__launch_bounds__(256)
__global__ void k2_gemm(const unsigned short* __restrict__ At,
                        const unsigned short* __restrict__ Bt,
                        unsigned short* __restrict__ Xt) {
    int lin = blockIdx.x + (blockIdx.y << 4);          // 2048 blocks
    int nlin = (lin & 7) * 256 + (lin >> 3);           // bijective XCD chunking
    const int p = nlin >> 4;
    const int tile = nlin & 15;
    const int i0 = (tile >> 2) * 128, j0 = (tile & 3) * 128;
    const unsigned short* Ap = At + (size_t)p * LL * LL + (size_t)i0 * LL;
    const unsigned short* Bp = Bt + (size_t)p * LL * LL + (size_t)j0 * LL;
    __shared__ unsigned short As[128][40], Bs[128][40];
    __shared__ unsigned short Cs[128][136];
    const int t = threadIdx.x, lane = t & 63, w = t >> 6;
    const int rsel = lane & 15, koff = lane >> 4;
    const int wm = w >> 1, wn = w & 1;

    f32x4 acc[4][4];
    #pragma unroll
    for (int i = 0; i < 4; ++i)
        #pragma unroll
        for (int j = 0; j < 4; ++j) acc[i][j] = (f32x4){0.f, 0.f, 0.f, 0.f};

    const int srow0 = t >> 2, skq = t & 3;
    uint4 ra[2], rb[2];
    #pragma unroll
    for (int q = 0; q < 2; ++q) {
        int row = srow0 + q * 64;
        ra[q] = *(const uint4*)&Ap[(size_t)row * LL + skq * 8];
        rb[q] = *(const uint4*)&Bp[(size_t)row * LL + skq * 8];
    }
    for (int k0 = 0; k0 < LL; k0 += 32) {
        #pragma unroll
        for (int q = 0; q < 2; ++q) {
            int row = srow0 + q * 64;
            *(uint4*)&As[row][skq * 8] = ra[q];
            *(uint4*)&Bs[row][skq * 8] = rb[q];
        }
        __syncthreads();
        if (k0 + 32 < LL) {
            #pragma unroll
            for (int q = 0; q < 2; ++q) {
                int row = srow0 + q * 64;
                ra[q] = *(const uint4*)&Ap[(size_t)row * LL + (k0 + 32) + skq * 8];
                rb[q] = *(const uint4*)&Bp[(size_t)row * LL + (k0 + 32) + skq * 8];
            }
        }
        bf16x8 af[4], bfr[4];
        #pragma unroll
        for (int mi = 0; mi < 4; ++mi)
            af[mi] = *(const bf16x8*)&As[wm * 64 + mi * 16 + rsel][koff * 8];
        #pragma unroll
        for (int ni = 0; ni < 4; ++ni)
            bfr[ni] = *(const bf16x8*)&Bs[wn * 64 + ni * 16 + rsel][koff * 8];
        #pragma unroll
        for (int mi = 0; mi < 4; ++mi)
            #pragma unroll
            for (int ni = 0; ni < 4; ++ni)
                acc[mi][ni] = MFMA16(af[mi], bfr[ni], acc[mi][ni]);
        __syncthreads();
    }
    const float s = 1.0f / (sqrtf((float)LL) + 1e-8f);
    #pragma unroll
    for (int mi = 0; mi < 4; ++mi)
        #pragma unroll
        for (int ni = 0; ni < 4; ++ni)
            #pragma unroll
            for (int r = 0; r < 4; ++r)
                Cs[wm * 64 + mi * 16 + koff * 4 + r][wn * 64 + ni * 16 + rsel] =
                    f2bf(acc[mi][ni][r] * s);
    __syncthreads();
    #pragma unroll
    for (int it = 0; it < 8; ++it) {
        int row = it * 16 + (t >> 4), colc = (t & 15) * 8;
        uint4 v = *(const uint4*)&Cs[row][colc];
        *(uint4*)&Xt[((size_t)p * LL + i0 + row) * LL + j0 + colc] = v;
    }
}

// ----------------------------- k3: transpose + LN + out-proj + gate + res ---
__launch_bounds__(256)
__global__ void k3_out(const unsigned short* __restrict__ Xt, const unsigned short* __restrict__ G,
                       const float* __restrict__ pairIn, const unsigned short* __restrict__ WoutB,
                       const float* __restrict__ lno_g, const float* __restrict__ lno_b,
                       const float* __restrict__ bout, float* __restrict__ out) {
    const int bb = blockIdx.z, irow = blockIdx.y, c0 = blockIdx.x * 128;
    const int t = threadIdx.x, w = t >> 6, lane = t & 63;
    __shared__ unsigned short x1[64][128];   // [d][c] staging, reused as o_lds [128][64]
    __shared__ unsigned short x2[128][72];   // [c][d] transposed

    #pragma unroll
    for (int q = 0; q < 4; ++q) {
        int idx = t + q * 256, d = idx >> 4, c8 = idx & 15;
        uint4 v = *(const uint4*)&Xt[((size_t)(bb * 64 + d) * LL + irow) * LL + c0 + c8 * 8];
        *(uint4*)&x1[d][c8 * 8] = v;
    }
    __syncthreads();
    {
        const int c = t & 127, half = t >> 7;
        unsigned short tmp[32];
        #pragma unroll
        for (int dd = 0; dd < 32; ++dd) tmp[dd] = x1[half * 32 + dd][c];
        #pragma unroll
        for (int q = 0; q < 4; ++q)
            *(uint4*)&x2[c][half * 32 + q * 8] = *(const uint4*)&tmp[q * 8];
    }
    __syncthreads();

    const float lg = lno_g[lane], lb = lno_b[lane];
    for (int r = w; r < 128; r += 4) {
        float v = bf2f(x2[r][lane]);
        float s = v, s2 = v * v;
        #pragma unroll
        for (int off = 32; off > 0; off >>= 1) {
            s += __shfl_xor(s, off);
            s2 += __shfl_xor(s2, off);
        }
        float m = s * 0.015625f;
        float var = s2 * 0.015625f - m * m;
        float rstd = rsqrtf(var + 1e-5f);
        x2[r][lane] = f2bf((v - m) * rstd * lg + lb);
    }
    __syncthreads();

    unsigned short* o_lds = &x1[0][0];   // [128][64]
    const int rsel = lane & 15, koff = lane >> 4;
    #pragma unroll
    for (int mh = 0; mh < 2; ++mh) {
        const int mi = 2 * w + mh;
        bf16x8 a0 = *(const bf16x8*)&x2[mi * 16 + rsel][koff * 8];
        bf16x8 a1 = *(const bf16x8*)&x2[mi * 16 + rsel][32 + koff * 8];
        #pragma unroll
        for (int n = 0; n < 4; ++n) {
            f32x4 pacc = {0.f, 0.f, 0.f, 0.f};
            const unsigned short* wrow = WoutB + (size_t)(n * 16 + rsel) * 64;
            pacc = MFMA16(a0, *(const bf16x8*)&wrow[koff * 8], pacc);
            pacc = MFMA16(a1, *(const bf16x8*)&wrow[32 + koff * 8], pacc);
            const float bo = bout[n * 16 + rsel];
            #pragma unroll
            for (int r = 0; r < 4; ++r)
                o_lds[(mi * 16 + koff * 4 + r) * 64 + n * 16 + rsel] = f2bf(pacc[r] + bo);
        }
    }
    __syncthreads();

    #pragma unroll
    for (int q = 0; q < 4; ++q) {
        int e = q * 2048 + t * 8;
        int c = e >> 6, o = e & 63;
        size_t pos = (size_t)(bb * LL + irow) * LL + c0 + c;
        uint4 ov = *(const uint4*)&o_lds[c * 64 + o];
        uint4 gv = *(const uint4*)&G[pos * DD + o];
        const unsigned short* ovp = (const unsigned short*)&ov;
        const unsigned short* gvp = (const unsigned short*)&gv;
        float4 p0 = *(const float4*)&pairIn[pos * DD + o];
        float4 p1 = *(const float4*)&pairIn[pos * DD + o + 4];
        float4 r0, r1;
        r0.x = p0.x + bf2f(ovp[0]) * bf2f(gvp[0]);
        r0.y = p0.y + bf2f(ovp[1]) * bf2f(gvp[1]);
        r0.z = p0.z + bf2f(ovp[2]) * bf2f(gvp[2]);
        r0.w = p0.w + bf2f(ovp[3]) * bf2f(gvp[3]);
        r1.x = p1.x + bf2f(ovp[4]) * bf2f(gvp[4]);
        r1.y = p1.y + bf2f(ovp[5]) * bf2f(gvp[5]);
        r1.z = p1.z + bf2f(ovp[6]) * bf2f(gvp[6]);
        r1.w = p1.w + bf2f(ovp[7]) * bf2f(gvp[7]);
        *(float4*)&out[pos * DD + o] = r0;
        *(float4*)&out[pos * DD + o + 4] = r1;
    }
}

// ----------------------------------------------------------------- launch ---
extern "C" void kernel_launch(void* const* d_in, const int* in_sizes, int n_in,
                              void* d_out, int out_size, void* d_ws, size_t ws_size,
                              hipStream_t stream) {
    const float* pair    = (const float*)d_in[0];
    const float* torsion = (const float*)d_in[1];
    const float* ln_g    = (const float*)d_in[2];
    const float* ln_b    = (const float*)d_in[3];
    const float* Wl      = (const float*)d_in[4];
    const float* Wr      = (const float*)d_in[5];
    const float* Wlg     = (const float*)d_in[6];
    const float* blg     = (const float*)d_in[7];
    const float* Wrg     = (const float*)d_in[8];
    const float* brg     = (const float*)d_in[9];
    const float* Wog     = (const float*)d_in[10];
    const float* bog     = (const float*)d_in[11];
    const float* Wout    = (const float*)d_in[12];
    const float* bout    = (const float*)d_in[13];
    const float* lno_g   = (const float*)d_in[14];
    const float* lno_b   = (const float*)d_in[15];
    const float* Wt      = (const float*)d_in[16];
    const float* bt      = (const float*)d_in[17];
    float* outp = (float*)d_out;

    const size_t PLANE_B = (size_t)128 * LL * LL * 2;   // 64 MiB per block
    const size_t need = 4 * PLANE_B + (320 * 64 + 64 * 64) * 2;
    if (ws_size < need) return;

    char* ws = (char*)d_ws;
    unsigned short* At    = (unsigned short*)(ws);
    unsigned short* Bt_   = (unsigned short*)(ws + PLANE_B);
    unsigned short* G     = (unsigned short*)(ws + 2 * PLANE_B);
    unsigned short* Xt    = (unsigned short*)(ws + 3 * PLANE_B);
    unsigned short* Wcat  = (unsigned short*)(ws + 4 * PLANE_B);
    unsigned short* WoutB = Wcat + 320 * 64;

    prep_w<<<dim3(40), dim3(256), 0, stream>>>(Wl, Wr, Wlg, Wrg, Wog, Wout, Wcat, WoutB);
    k1_proj<<<dim3(4, LL, 2), dim3(256), 0, stream>>>(pair, torsion, ln_g, ln_b, blg, brg,
                                                      bog, Wt, bt, Wcat, At, Bt_, G);
    k2_gemm<<<dim3(16, 128), dim3(256), 0, stream>>>(At, Bt_, Xt);
    k3_out<<<dim3(4, LL, 2), dim3(256), 0, stream>>>(Xt, G, pair, WoutB, lno_g, lno_b, bout, outp);
}

// Round 5
// 439.944 us; speedup vs baseline: 1.2431x; 1.0134x over previous
//
#include <hip/hip_runtime.h>
#include <stdint.h>

#define LL 512
#define DD 64

typedef __attribute__((ext_vector_type(8))) short bf16x8;
typedef __attribute__((ext_vector_type(4))) float f32x4;

#define MFMA16(a, b, c) __builtin_amdgcn_mfma_f32_16x16x32_bf16((a), (b), (c), 0, 0, 0)

__device__ __forceinline__ float bf2f(unsigned short u) {
    union { unsigned int i; float f; } v; v.i = ((unsigned int)u) << 16; return v.f;
}
__device__ __forceinline__ unsigned short f2bf(float f) {
    union { float f; unsigned int i; } v; v.f = f;
    unsigned int i = v.i;
    return (unsigned short)((i + 0x7FFFu + ((i >> 16) & 1u)) >> 16);  // RNE
}
// Round-3 lesson: raw rcpf regressed absmax 0.031->0.203. Newton-refined rcp
// is <=1ulp of exact division (y*(2-d*y) refinement) -- numerically safe,
// ~5 ops instead of ~10 for the full div expansion.
__device__ __forceinline__ float sigm(float x) {
    float d = 1.0f + __expf(-x);
    float y = __builtin_amdgcn_rcpf(d);
    return y * __builtin_fmaf(-d, y, 2.0f);
}

// ---------------------------------------------------------------- prep ------
__global__ void prep_w(const float* __restrict__ Wl, const float* __restrict__ Wr,
                       const float* __restrict__ Wlg, const float* __restrict__ Wrg,
                       const float* __restrict__ Wog, const float* __restrict__ Wout,
                       unsigned short* __restrict__ Wcat, unsigned short* __restrict__ WoutB) {
    int t = threadIdx.x + blockIdx.x * blockDim.x;
    int stride = blockDim.x * gridDim.x;
    for (int idx = t; idx < 320 * 64; idx += stride) {
        int row = idx >> 6, col = idx & 63;
        int sec = row >> 6, r = row & 63;
        float v;
        switch (sec) {
            case 0:  v = Wl[r * 64 + col];  break;
            case 1:  v = Wlg[r * 64 + col]; break;
            case 2:  v = Wr[r * 64 + col];  break;
            case 3:  v = Wrg[r * 64 + col]; break;
            default: v = Wog[r * 64 + col]; break;
        }
        Wcat[idx] = f2bf(v);
    }
    for (int idx = t; idx < 64 * 64; idx += stride) WoutB[idx] = f2bf(Wout[idx]);
}

// ------------------------------------------------- k1: LN + proj + gates ----
// Wave w owns output-channel group (cols w*16..w*16+15) for all position
// tiles; weight fragments live in registers (loaded once, reused 8x).
// Round-5: At/Bt transpose-staging split into two 64-pos halves -> LDS
// 52->35KB -> 4 blocks/CU (was 3); sigmoid uses Newton-refined rcp.
__launch_bounds__(256)
__global__ void k1_proj(const float* __restrict__ pair, const float* __restrict__ torsion,
                        const float* __restrict__ ln_g, const float* __restrict__ ln_b,
                        const float* __restrict__ blg, const float* __restrict__ brg,
                        const float* __restrict__ bog, const float* __restrict__ Wt,
                        const float* __restrict__ bt, const unsigned short* __restrict__ Wcat,
                        unsigned short* __restrict__ At, unsigned short* __restrict__ Bt,
                        unsigned short* __restrict__ G) {
    const int bb = blockIdx.z, irow = blockIdx.y, c0 = blockIdx.x * 128;
    const int t = threadIdx.x, w = t >> 6, lane = t & 63;
    const int rsel = lane & 15, koff = lane >> 4;
    const int col = w * 16 + rsel;            // this wave's output channel
    __shared__ unsigned short zs[128][72];    // z bf16 [pos][d]; later reused for G
    __shared__ unsigned short awL[64][68];    // aw d-major [d][pos-in-half]
    __shared__ unsigned short bL[64][68];     // b  d-major [d][pos-in-half]

    float tww;
    {
        float acc = bt[0];
        #pragma unroll
        for (int n = 0; n < 6; ++n) acc += torsion[(bb * LL + irow) * 6 + n] * Wt[n];
        tww = sigm(acc);
    }

    // Hoisted weight fragments: 5 matrices x 2 k-halves, 16B each (40 VGPR).
    bf16x8 wfr[5][2];
    #pragma unroll
    for (int s = 0; s < 5; ++s)
        #pragma unroll
        for (int kh = 0; kh < 2; ++kh)
            wfr[s][kh] = *(const bf16x8*)&Wcat[(size_t)(s * 64 + col) * 64 + kh * 32 + koff * 8];
    const float vblg = blg[col], vbrg = brg[col], vbog = bog[col];

    // ---- LN (validated form): one row per wave pass, lane = d ----
    const float lg = ln_g[lane], lb = ln_b[lane];
    const float* prow = pair + ((size_t)(bb * LL + irow) * LL + c0) * DD;
    for (int r = w; r < 128; r += 4) {
        float v = prow[r * DD + lane];
        float s = v, s2 = v * v;
        #pragma unroll
        for (int off = 32; off > 0; off >>= 1) {
            s += __shfl_xor(s, off);
            s2 += __shfl_xor(s2, off);
        }
        float m = s * 0.015625f;
        float var = s2 * 0.015625f - m * m;
        float rstd = rsqrtf(var + 1e-5f);
        zs[r][lane] = f2bf((v - m) * rstd * lg + lb);
    }
    __syncthreads();

    // ---- projections: 2 halves x 4 position tiles, weights in registers ----
    ushort4 gk[8];
    #pragma unroll
    for (int h = 0; h < 2; ++h) {
        #pragma unroll
        for (int mt = 0; mt < 4; ++mt) {
            const int mi = h * 4 + mt;
            bf16x8 a0 = *(const bf16x8*)&zs[mi * 16 + rsel][koff * 8];
            bf16x8 a1 = *(const bf16x8*)&zs[mi * 16 + rsel][32 + koff * 8];
            f32x4 pl = {0.f, 0.f, 0.f, 0.f}, plg = pl, pr = pl, prg = pl, pog = pl;
            pl  = MFMA16(a0, wfr[0][0], pl);  pl  = MFMA16(a1, wfr[0][1], pl);
            plg = MFMA16(a0, wfr[1][0], plg); plg = MFMA16(a1, wfr[1][1], plg);
            pr  = MFMA16(a0, wfr[2][0], pr);  pr  = MFMA16(a1, wfr[2][1], pr);
            prg = MFMA16(a0, wfr[3][0], prg); prg = MFMA16(a1, wfr[3][1], prg);
            pog = MFMA16(a0, wfr[4][0], pog); pog = MFMA16(a1, wfr[4][1], pog);

            const int crow = mt * 16 + koff * 4;   // position within half
            unsigned short aw4[4], bm4[4], g4[4];
            #pragma unroll
            for (int r = 0; r < 4; ++r) {
                float av = pl[r] * sigm(plg[r] + vblg) * tww;
                float bv = pr[r] * sigm(prg[r] + vbrg);
                float gv = sigm(pog[r] + vbog);
                aw4[r] = f2bf(av); bm4[r] = f2bf(bv); g4[r] = f2bf(gv);
            }
            *(ushort4*)&awL[col][crow] = make_ushort4(aw4[0], aw4[1], aw4[2], aw4[3]);
            *(ushort4*)&bL[col][crow]  = make_ushort4(bm4[0], bm4[1], bm4[2], bm4[3]);
            gk[mi] = make_ushort4(g4[0], g4[1], g4[2], g4[3]);
        }
        __syncthreads();   // staging of this half complete (and, h==1: all z reads done)

        if (h == 1) {
            // Dump gate regs into zs (wave-private cells), [pos][d] == G layout.
            #pragma unroll
            for (int mi = 0; mi < 8; ++mi) {
                const int rbase = mi * 16 + koff * 4;
                zs[rbase + 0][col] = gk[mi].x;
                zs[rbase + 1][col] = gk[mi].y;
                zs[rbase + 2][col] = gk[mi].z;
                zs[rbase + 3][col] = gk[mi].w;
            }
        }

        // Coalesced write-out of this half: 64 d-rows x 64 pos (128B/16-lane).
        #pragma unroll
        for (int it = 0; it < 4; ++it) {
            int d = it * 16 + (t >> 4);
            int c4 = (t & 15) * 4;
            size_t base = ((size_t)(bb * 64 + d) * LL + irow) * LL + c0 + h * 64 + c4;
            *(ushort4*)&At[base] = *(const ushort4*)&awL[d][c4];
            *(ushort4*)&Bt[base] = *(const ushort4*)&bL[d][c4];
        }
        __syncthreads();   // awL/bL free for next half; h==1: zs (G) complete
    }

    // G: one contiguous 16KB block, [pos][d].
    #pragma unroll
    for (int it = 0; it < 8; ++it) {
        int r = it * 16 + (t >> 4), cc = (t & 15) * 4;
        size_t pos = (size_t)(bb * LL + irow) * LL + c0 + r;
        *(ushort4*)&G[pos * DD + cc] = *(const ushort4*)&zs[r][cc];
    }
}

// ------------------------------------------ k2: batched plane GEMM (AB^T) ---
// grid: x = 16 tiles (4x4 of 128x128), y = 128 planes. 256 threads = 4 waves.
// XCD-chunked bijective swizzle (2048 % 8 == 0) for L2 panel reuse.
__launch_bounds__(256)
__global__ void k2_gemm(const unsigned short* __restrict__ At,
                        const unsigned short* __restrict__ Bt,
                        unsigned short* __restrict__ Xt) {
    int lin = blockIdx.x + (blockIdx.y << 4);          // 2048 blocks
    int nlin = (lin & 7) * 256 + (lin >> 3);           // bijective XCD chunking
    const int p = nlin >> 4;
    const int tile = nlin & 15;
    const int i0 = (tile >> 2) * 128, j0 = (tile & 3) * 128;
    const unsigned short* Ap = At + (size_t)p * LL * LL + (size_t)i0 * LL;
    const unsigned short* Bp = Bt + (size_t)p * LL * LL + (size_t)j0 * LL;
    __shared__ unsigned short As[128][40], Bs[128][40];
    __shared__ unsigned short Cs[128][136];
    const int t = threadIdx.x, lane = t & 63, w = t >> 6;
    const int rsel = lane & 15, koff = lane >> 4;
    const int wm = w >> 1, wn = w & 1;

    f32x4 acc[4][4];
    #pragma unroll
    for (int i = 0; i < 4; ++i)
        #pragma unroll
        for (int j = 0; j < 4; ++j) acc[i][j] = (f32x4){0.f, 0.f, 0.f, 0.f};

    const int srow0 = t >> 2, skq = t & 3;
    uint4 ra[2], rb[2];
    #pragma unroll
    for (int q = 0; q < 2; ++q) {
        int row = srow0 + q * 64;
        ra[q] = *(const uint4*)&Ap[(size_t)row * LL + skq * 8];
        rb[q] = *(const uint4*)&Bp[(size_t)row * LL + skq * 8];
    }
    for (int k0 = 0; k0 < LL; k0 += 32) {
        #pragma unroll
        for (int q = 0; q < 2; ++q) {
            int row = srow0 + q * 64;
            *(uint4*)&As[row][skq * 8] = ra[q];
            *(uint4*)&Bs[row][skq * 8] = rb[q];
        }
        __syncthreads();
        if (k0 + 32 < LL) {
            #pragma unroll
            for (int q = 0; q < 2; ++q) {
                int row = srow0 + q * 64;
                ra[q] = *(const uint4*)&Ap[(size_t)row * LL + (k0 + 32) + skq * 8];
                rb[q] = *(const uint4*)&Bp[(size_t)row * LL + (k0 + 32) + skq * 8];
            }
        }
        bf16x8 af[4], bfr[4];
        #pragma unroll
        for (int mi = 0; mi < 4; ++mi)
            af[mi] = *(const bf16x8*)&As[wm * 64 + mi * 16 + rsel][koff * 8];
        #pragma unroll
        for (int ni = 0; ni < 4; ++ni)
            bfr[ni] = *(const bf16x8*)&Bs[wn * 64 + ni * 16 + rsel][koff * 8];
        #pragma unroll
        for (int mi = 0; mi < 4; ++mi)
            #pragma unroll
            for (int ni = 0; ni < 4; ++ni)
                acc[mi][ni] = MFMA16(af[mi], bfr[ni], acc[mi][ni]);
        __syncthreads();
    }
    const float s = 1.0f / (sqrtf((float)LL) + 1e-8f);
    #pragma unroll
    for (int mi = 0; mi < 4; ++mi)
        #pragma unroll
        for (int ni = 0; ni < 4; ++ni)
            #pragma unroll
            for (int r = 0; r < 4; ++r)
                Cs[wm * 64 + mi * 16 + koff * 4 + r][wn * 64 + ni * 16 + rsel] =
                    f2bf(acc[mi][ni][r] * s);
    __syncthreads();
    #pragma unroll
    for (int it = 0; it < 8; ++it) {
        int row = it * 16 + (t >> 4), colc = (t & 15) * 8;
        uint4 v = *(const uint4*)&Cs[row][colc];
        *(uint4*)&Xt[((size_t)p * LL + i0 + row) * LL + j0 + colc] = v;
    }
}

// ----------------------------- k3: transpose + LN + out-proj + gate + res ---
__launch_bounds__(256)
__global__ void k3_out(const unsigned short* __restrict__ Xt, const unsigned short* __restrict__ G,
                       const float* __restrict__ pairIn, const unsigned short* __restrict__ WoutB,
                       const float* __restrict__ lno_g, const float* __restrict__ lno_b,
                       const float* __restrict__ bout, float* __restrict__ out) {
    const int bb = blockIdx.z, irow = blockIdx.y, c0 = blockIdx.x * 128;
    const int t = threadIdx.x, w = t >> 6, lane = t & 63;
    __shared__ unsigned short x1[64][128];   // [d][c] staging, reused as o_lds [128][64]
    __shared__ unsigned short x2[128][72];   // [c][d] transposed

    #pragma unroll
    for (int q = 0; q < 4; ++q) {
        int idx = t + q * 256, d = idx >> 4, c8 = idx & 15;
        uint4 v = *(const uint4*)&Xt[((size_t)(bb * 64 + d) * LL + irow) * LL + c0 + c8 * 8];
        *(uint4*)&x1[d][c8 * 8] = v;
    }
    __syncthreads();
    {
        const int c = t & 127, half = t >> 7;
        unsigned short tmp[32];
        #pragma unroll
        for (int dd = 0; dd < 32; ++dd) tmp[dd] = x1[half * 32 + dd][c];
        #pragma unroll
        for (int q = 0; q < 4; ++q)
            *(uint4*)&x2[c][half * 32 + q * 8] = *(const uint4*)&tmp[q * 8];
    }
    __syncthreads();

    const float lg = lno_g[lane], lb = lno_b[lane];
    for (int r = w; r < 128; r += 4) {
        float v = bf2f(x2[r][lane]);
        float s = v, s2 = v * v;
        #pragma unroll
        for (int off = 32; off > 0; off >>= 1) {
            s += __shfl_xor(s, off);
            s2 += __shfl_xor(s2, off);
        }
        float m = s * 0.015625f;
        float var = s2 * 0.015625f - m * m;
        float rstd = rsqrtf(var + 1e-5f);
        x2[r][lane] = f2bf((v - m) * rstd * lg + lb);
    }
    __syncthreads();

    unsigned short* o_lds = &x1[0][0];   // [128][64]
    const int rsel = lane & 15, koff = lane >> 4;
    #pragma unroll
    for (int mh = 0; mh < 2; ++mh) {
        const int mi = 2 * w + mh;
        bf16x8 a0 = *(const bf16x8*)&x2[mi * 16 + rsel][koff * 8];
        bf16x8 a1 = *(const bf16x8*)&x2[mi * 16 + rsel][32 + koff * 8];
        #pragma unroll
        for (int n = 0; n < 4; ++n) {
            f32x4 pacc = {0.f, 0.f, 0.f, 0.f};
            const unsigned short* wrow = WoutB + (size_t)(n * 16 + rsel) * 64;
            pacc = MFMA16(a0, *(const bf16x8*)&wrow[koff * 8], pacc);
            pacc = MFMA16(a1, *(const bf16x8*)&wrow[32 + koff * 8], pacc);
            const float bo = bout[n * 16 + rsel];
            #pragma unroll
            for (int r = 0; r < 4; ++r)
                o_lds[(mi * 16 + koff * 4 + r) * 64 + n * 16 + rsel] = f2bf(pacc[r] + bo);
        }
    }
    __syncthreads();

    #pragma unroll
    for (int q = 0; q < 4; ++q) {
        int e = q * 2048 + t * 8;
        int c = e >> 6, o = e & 63;
        size_t pos = (size_t)(bb * LL + irow) * LL + c0 + c;
        uint4 ov = *(const uint4*)&o_lds[c * 64 + o];
        uint4 gv = *(const uint4*)&G[pos * DD + o];
        const unsigned short* ovp = (const unsigned short*)&ov;
        const unsigned short* gvp = (const unsigned short*)&gv;
        float4 p0 = *(const float4*)&pairIn[pos * DD + o];
        float4 p1 = *(const float4*)&pairIn[pos * DD + o + 4];
        float4 r0, r1;
        r0.x = p0.x + bf2f(ovp[0]) * bf2f(gvp[0]);
        r0.y = p0.y + bf2f(ovp[1]) * bf2f(gvp[1]);
        r0.z = p0.z + bf2f(ovp[2]) * bf2f(gvp[2]);
        r0.w = p0.w + bf2f(ovp[3]) * bf2f(gvp[3]);
        r1.x = p1.x + bf2f(ovp[4]) * bf2f(gvp[4]);
        r1.y = p1.y + bf2f(ovp[5]) * bf2f(gvp[5]);
        r1.z = p1.z + bf2f(ovp[6]) * bf2f(gvp[6]);
        r1.w = p1.w + bf2f(ovp[7]) * bf2f(gvp[7]);
        *(float4*)&out[pos * DD + o] = r0;
        *(float4*)&out[pos * DD + o + 4] = r1;
    }
}

// ----------------------------------------------------------------- launch ---
extern "C" void kernel_launch(void* const* d_in, const int* in_sizes, int n_in,
                              void* d_out, int out_size, void* d_ws, size_t ws_size,
                              hipStream_t stream) {
    const float* pair    = (const float*)d_in[0];
    const float* torsion = (const float*)d_in[1];
    const float* ln_g    = (const float*)d_in[2];
    const float* ln_b    = (const float*)d_in[3];
    const float* Wl      = (const float*)d_in[4];
    const float* Wr      = (const float*)d_in[5];
    const float* Wlg     = (const float*)d_in[6];
    const float* blg     = (const float*)d_in[7];
    const float* Wrg     = (const float*)d_in[8];
    const float* brg     = (const float*)d_in[9];
    const float* Wog     = (const float*)d_in[10];
    const float* bog     = (const float*)d_in[11];
    const float* Wout    = (const float*)d_in[12];
    const float* bout    = (const float*)d_in[13];
    const float* lno_g   = (const float*)d_in[14];
    const float* lno_b   = (const float*)d_in[15];
    const float* Wt      = (const float*)d_in[16];
    const float* bt      = (const float*)d_in[17];
    float* outp = (float*)d_out;

    const size_t PLANE_B = (size_t)128 * LL * LL * 2;   // 64 MiB per block
    const size_t need = 4 * PLANE_B + (320 * 64 + 64 * 64) * 2;
    if (ws_size < need) return;

    char* ws = (char*)d_ws;
    unsigned short* At    = (unsigned short*)(ws);
    unsigned short* Bt_   = (unsigned short*)(ws + PLANE_B);
    unsigned short* G     = (unsigned short*)(ws + 2 * PLANE_B);
    unsigned short* Xt    = (unsigned short*)(ws + 3 * PLANE_B);
    unsigned short* Wcat  = (unsigned short*)(ws + 4 * PLANE_B);
    unsigned short* WoutB = Wcat + 320 * 64;

    prep_w<<<dim3(40), dim3(256), 0, stream>>>(Wl, Wr, Wlg, Wrg, Wog, Wout, Wcat, WoutB);
    k1_proj<<<dim3(4, LL, 2), dim3(256), 0, stream>>>(pair, torsion, ln_g, ln_b, blg, brg,
                                                      bog, Wt, bt, Wcat, At, Bt_, G);
    k2_gemm<<<dim3(16, 128), dim3(256), 0, stream>>>(At, Bt_, Xt);
    k3_out<<<dim3(4, LL, 2), dim3(256), 0, stream>>>(Xt, G, pair, WoutB, lno_g, lno_b, bout, outp);
}

// Round 6
// 283.609 us; speedup vs baseline: 1.9284x; 1.5512x over previous
//
#include <hip/hip_runtime.h>
#include <stdint.h>

#define LL 512
#define DD 64

typedef __attribute__((ext_vector_type(8))) short bf16x8;
typedef __attribute__((ext_vector_type(4))) float f32x4;

#define MFMA16(a, b, c) __builtin_amdgcn_mfma_f32_16x16x32_bf16((a), (b), (c), 0, 0, 0)

__device__ __forceinline__ float bf2f(unsigned short u) {
    union { unsigned int i; float f; } v; v.i = ((unsigned int)u) << 16; return v.f;
}
__device__ __forceinline__ unsigned short f2bf(float f) {
    union { float f; unsigned int i; } v; v.f = f;
    unsigned int i = v.i;
    return (unsigned short)((i + 0x7FFFu + ((i >> 16) & 1u)) >> 16);  // RNE
}
// Newton-refined rcp sigmoid: validated rounds 5 (absmax identical to exact
// division). Raw rcpf without refinement is banned (round-3 regression).
__device__ __forceinline__ float sigm(float x) {
    float d = 1.0f + __expf(-x);
    float y = __builtin_amdgcn_rcpf(d);
    return y * __builtin_fmaf(-d, y, 2.0f);
}

// ---------------------------------------------------------------- prep ------
__global__ void prep_w(const float* __restrict__ Wl, const float* __restrict__ Wr,
                       const float* __restrict__ Wlg, const float* __restrict__ Wrg,
                       const float* __restrict__ Wog, const float* __restrict__ Wout,
                       unsigned short* __restrict__ Wcat, unsigned short* __restrict__ WoutB) {
    int t = threadIdx.x + blockIdx.x * blockDim.x;
    int stride = blockDim.x * gridDim.x;
    for (int idx = t; idx < 320 * 64; idx += stride) {
        int row = idx >> 6, col = idx & 63;
        int sec = row >> 6, r = row & 63;
        float v;
        switch (sec) {
            case 0:  v = Wl[r * 64 + col];  break;
            case 1:  v = Wlg[r * 64 + col]; break;
            case 2:  v = Wr[r * 64 + col];  break;
            case 3:  v = Wrg[r * 64 + col]; break;
            default: v = Wog[r * 64 + col]; break;
        }
        Wcat[idx] = f2bf(v);
    }
    for (int idx = t; idx < 64 * 64; idx += stride) WoutB[idx] = f2bf(Wout[idx]);
}

// ------------------------------------------------- k1: LN + proj + gates ----
// Wave w owns output-channel group (cols w*16..w*16+15) for all 8 position
// tiles; weight fragments in registers (loaded once, reused 8x).
// Round-6: (a) revert h-split (its barriers drained vmcnt(0) after global
// stores -> VALUBusy fell 35->27); single-barrier round-4 tail structure.
// (b) LN via 4-lane groups: 16 elems/lane in regs, float4 loads, 2 shuffle
// levels instead of 6x2 per row (384 -> 8 cross-lane ops per wave).
__launch_bounds__(256)
__global__ void k1_proj(const float* __restrict__ pair, const float* __restrict__ torsion,
                        const float* __restrict__ ln_g, const float* __restrict__ ln_b,
                        const float* __restrict__ blg, const float* __restrict__ brg,
                        const float* __restrict__ bog, const float* __restrict__ Wt,
                        const float* __restrict__ bt, const unsigned short* __restrict__ Wcat,
                        unsigned short* __restrict__ At, unsigned short* __restrict__ Bt,
                        unsigned short* __restrict__ G) {
    const int bb = blockIdx.z, irow = blockIdx.y, c0 = blockIdx.x * 128;
    const int t = threadIdx.x, w = t >> 6, lane = t & 63;
    const int rsel = lane & 15, koff = lane >> 4;
    const int col = w * 16 + rsel;            // this wave's output channel
    __shared__ unsigned short zs[128][72];    // z bf16 [pos][d]; later reused for G
    __shared__ unsigned short awL[64][132];   // aw d-major [d][pos]
    __shared__ unsigned short bL[64][132];    // b  d-major [d][pos]

    float tww;
    {
        float acc = bt[0];
        #pragma unroll
        for (int n = 0; n < 6; ++n) acc += torsion[(bb * LL + irow) * 6 + n] * Wt[n];
        tww = sigm(acc);
    }

    // Hoisted weight fragments: 5 matrices x 2 k-halves, 16B each (40 VGPR).
    bf16x8 wfr[5][2];
    #pragma unroll
    for (int s = 0; s < 5; ++s)
        #pragma unroll
        for (int kh = 0; kh < 2; ++kh)
            wfr[s][kh] = *(const bf16x8*)&Wcat[(size_t)(s * 64 + col) * 64 + kh * 32 + koff * 8];
    const float vblg = blg[col], vbrg = brg[col], vbog = bog[col];

    // ---- LN: 4 lanes per row, 16 elems/lane in registers, 2 shuffle levels --
    {
        const int sub = lane & 3, rr = lane >> 2;
        const float4* pr4 = (const float4*)(pair + ((size_t)(bb * LL + irow) * LL + c0) * DD);
        #pragma unroll
        for (int p = 0; p < 2; ++p) {
            const int row = w * 32 + p * 16 + rr;
            float4 x[4];
            #pragma unroll
            for (int q = 0; q < 4; ++q) x[q] = pr4[row * 16 + sub * 4 + q];
            float s = 0.f, s2 = 0.f;
            #pragma unroll
            for (int q = 0; q < 4; ++q) {
                s += x[q].x + x[q].y + x[q].z + x[q].w;
                s2 += x[q].x * x[q].x + x[q].y * x[q].y + x[q].z * x[q].z + x[q].w * x[q].w;
            }
            s += __shfl_xor(s, 1);  s2 += __shfl_xor(s2, 1);
            s += __shfl_xor(s, 2);  s2 += __shfl_xor(s2, 2);
            float m = s * 0.015625f;
            float var = s2 * 0.015625f - m * m;
            float rstd = rsqrtf(var + 1e-5f);
            #pragma unroll
            for (int q = 0; q < 4; ++q) {
                float4 lg4 = ((const float4*)ln_g)[sub * 4 + q];
                float4 lb4 = ((const float4*)ln_b)[sub * 4 + q];
                ushort4 zw;
                zw.x = f2bf((x[q].x - m) * rstd * lg4.x + lb4.x);
                zw.y = f2bf((x[q].y - m) * rstd * lg4.y + lb4.y);
                zw.z = f2bf((x[q].z - m) * rstd * lg4.z + lb4.z);
                zw.w = f2bf((x[q].w - m) * rstd * lg4.w + lb4.w);
                *(ushort4*)&zs[row][sub * 16 + q * 4] = zw;
            }
        }
    }
    __syncthreads();

    // ---- projections: 8 position tiles, weights stay in registers ----
    ushort4 gk[8];
    #pragma unroll
    for (int mi = 0; mi < 8; ++mi) {
        bf16x8 a0 = *(const bf16x8*)&zs[mi * 16 + rsel][koff * 8];
        bf16x8 a1 = *(const bf16x8*)&zs[mi * 16 + rsel][32 + koff * 8];
        f32x4 pl = {0.f, 0.f, 0.f, 0.f}, plg = pl, pr = pl, prg = pl, pog = pl;
        pl  = MFMA16(a0, wfr[0][0], pl);  pl  = MFMA16(a1, wfr[0][1], pl);
        plg = MFMA16(a0, wfr[1][0], plg); plg = MFMA16(a1, wfr[1][1], plg);
        pr  = MFMA16(a0, wfr[2][0], pr);  pr  = MFMA16(a1, wfr[2][1], pr);
        prg = MFMA16(a0, wfr[3][0], prg); prg = MFMA16(a1, wfr[3][1], prg);
        pog = MFMA16(a0, wfr[4][0], pog); pog = MFMA16(a1, wfr[4][1], pog);

        const int crow = mi * 16 + koff * 4;
        unsigned short aw4[4], bm4[4], g4[4];
        #pragma unroll
        for (int r = 0; r < 4; ++r) {
            float av = pl[r] * sigm(plg[r] + vblg) * tww;
            float bv = pr[r] * sigm(prg[r] + vbrg);
            float gv = sigm(pog[r] + vbog);
            aw4[r] = f2bf(av); bm4[r] = f2bf(bv); g4[r] = f2bf(gv);
        }
        *(ushort4*)&awL[col][crow] = make_ushort4(aw4[0], aw4[1], aw4[2], aw4[3]);
        *(ushort4*)&bL[col][crow]  = make_ushort4(bm4[0], bm4[1], bm4[2], bm4[3]);
        gk[mi] = make_ushort4(g4[0], g4[1], g4[2], g4[3]);
    }
    __syncthreads();   // all waves done reading z from zs

    // Dump gate regs into zs (wave-private cells), [pos][d] == G layout.
    #pragma unroll
    for (int mi = 0; mi < 8; ++mi) {
        const int rbase = mi * 16 + koff * 4;
        zs[rbase + 0][col] = gk[mi].x;
        zs[rbase + 1][col] = gk[mi].y;
        zs[rbase + 2][col] = gk[mi].z;
        zs[rbase + 3][col] = gk[mi].w;
    }
    __syncthreads();

    // Tail: all global stores fire-and-forget (no barrier after this point).
    #pragma unroll
    for (int it = 0; it < 8; ++it) {
        int d = it * 8 + (t >> 5);
        int c8 = (t & 31) * 4;
        size_t base = ((size_t)(bb * 64 + d) * LL + irow) * LL + c0 + c8;
        *(ushort4*)&At[base] = *(const ushort4*)&awL[d][c8];
        *(ushort4*)&Bt[base] = *(const ushort4*)&bL[d][c8];
    }
    #pragma unroll
    for (int it = 0; it < 8; ++it) {
        int r = it * 16 + (t >> 4), cc = (t & 15) * 4;
        size_t pos = (size_t)(bb * LL + irow) * LL + c0 + r;
        *(ushort4*)&G[pos * DD + cc] = *(const ushort4*)&zs[r][cc];
    }
}

// ------------------------------------------ k2: batched plane GEMM (AB^T) ---
// grid: x = 16 tiles (4x4 of 128x128), y = 128 planes. 256 threads = 4 waves.
// XCD-chunked bijective swizzle (2048 % 8 == 0) for L2 panel reuse.
__launch_bounds__(256)
__global__ void k2_gemm(const unsigned short* __restrict__ At,
                        const unsigned short* __restrict__ Bt,
                        unsigned short* __restrict__ Xt) {
    int lin = blockIdx.x + (blockIdx.y << 4);          // 2048 blocks
    int nlin = (lin & 7) * 256 + (lin >> 3);           // bijective XCD chunking
    const int p = nlin >> 4;
    const int tile = nlin & 15;
    const int i0 = (tile >> 2) * 128, j0 = (tile & 3) * 128;
    const unsigned short* Ap = At + (size_t)p * LL * LL + (size_t)i0 * LL;
    const unsigned short* Bp = Bt + (size_t)p * LL * LL + (size_t)j0 * LL;
    __shared__ unsigned short As[128][40], Bs[128][40];
    __shared__ unsigned short Cs[128][136];
    const int t = threadIdx.x, lane = t & 63, w = t >> 6;
    const int rsel = lane & 15, koff = lane >> 4;
    const int wm = w >> 1, wn = w & 1;

    f32x4 acc[4][4];
    #pragma unroll
    for (int i = 0; i < 4; ++i)
        #pragma unroll
        for (int j = 0; j < 4; ++j) acc[i][j] = (f32x4){0.f, 0.f, 0.f, 0.f};

    const int srow0 = t >> 2, skq = t & 3;
    uint4 ra[2], rb[2];
    #pragma unroll
    for (int q = 0; q < 2; ++q) {
        int row = srow0 + q * 64;
        ra[q] = *(const uint4*)&Ap[(size_t)row * LL + skq * 8];
        rb[q] = *(const uint4*)&Bp[(size_t)row * LL + skq * 8];
    }
    for (int k0 = 0; k0 < LL; k0 += 32) {
        #pragma unroll
        for (int q = 0; q < 2; ++q) {
            int row = srow0 + q * 64;
            *(uint4*)&As[row][skq * 8] = ra[q];
            *(uint4*)&Bs[row][skq * 8] = rb[q];
        }
        __syncthreads();
        if (k0 + 32 < LL) {
            #pragma unroll
            for (int q = 0; q < 2; ++q) {
                int row = srow0 + q * 64;
                ra[q] = *(const uint4*)&Ap[(size_t)row * LL + (k0 + 32) + skq * 8];
                rb[q] = *(const uint4*)&Bp[(size_t)row * LL + (k0 + 32) + skq * 8];
            }
        }
        bf16x8 af[4], bfr[4];
        #pragma unroll
        for (int mi = 0; mi < 4; ++mi)
            af[mi] = *(const bf16x8*)&As[wm * 64 + mi * 16 + rsel][koff * 8];
        #pragma unroll
        for (int ni = 0; ni < 4; ++ni)
            bfr[ni] = *(const bf16x8*)&Bs[wn * 64 + ni * 16 + rsel][koff * 8];
        #pragma unroll
        for (int mi = 0; mi < 4; ++mi)
            #pragma unroll
            for (int ni = 0; ni < 4; ++ni)
                acc[mi][ni] = MFMA16(af[mi], bfr[ni], acc[mi][ni]);
        __syncthreads();
    }
    const float s = 1.0f / (sqrtf((float)LL) + 1e-8f);
    #pragma unroll
    for (int mi = 0; mi < 4; ++mi)
        #pragma unroll
        for (int ni = 0; ni < 4; ++ni)
            #pragma unroll
            for (int r = 0; r < 4; ++r)
                Cs[wm * 64 + mi * 16 + koff * 4 + r][wn * 64 + ni * 16 + rsel] =
                    f2bf(acc[mi][ni][r] * s);
    __syncthreads();
    #pragma unroll
    for (int it = 0; it < 8; ++it) {
        int row = it * 16 + (t >> 4), colc = (t & 15) * 8;
        uint4 v = *(const uint4*)&Cs[row][colc];
        *(uint4*)&Xt[((size_t)p * LL + i0 + row) * LL + j0 + colc] = v;
    }
}

// ----------------------------- k3: transpose + LN + out-proj + gate + res ---
// Round-6: LN switched to the same 4-lane-group reduction as k1.
__launch_bounds__(256)
__global__ void k3_out(const unsigned short* __restrict__ Xt, const unsigned short* __restrict__ G,
                       const float* __restrict__ pairIn, const unsigned short* __restrict__ WoutB,
                       const float* __restrict__ lno_g, const float* __restrict__ lno_b,
                       const float* __restrict__ bout, float* __restrict__ out) {
    const int bb = blockIdx.z, irow = blockIdx.y, c0 = blockIdx.x * 128;
    const int t = threadIdx.x, w = t >> 6, lane = t & 63;
    __shared__ unsigned short x1[64][128];   // [d][c] staging, reused as o_lds [128][64]
    __shared__ unsigned short x2[128][72];   // [c][d] transposed

    #pragma unroll
    for (int q = 0; q < 4; ++q) {
        int idx = t + q * 256, d = idx >> 4, c8 = idx & 15;
        uint4 v = *(const uint4*)&Xt[((size_t)(bb * 64 + d) * LL + irow) * LL + c0 + c8 * 8];
        *(uint4*)&x1[d][c8 * 8] = v;
    }
    __syncthreads();
    {
        const int c = t & 127, half = t >> 7;
        unsigned short tmp[32];
        #pragma unroll
        for (int dd = 0; dd < 32; ++dd) tmp[dd] = x1[half * 32 + dd][c];
        #pragma unroll
        for (int q = 0; q < 4; ++q)
            *(uint4*)&x2[c][half * 32 + q * 8] = *(const uint4*)&tmp[q * 8];
    }
    __syncthreads();

    // ---- LN: 4 lanes per row, 16 elems/lane, 2 shuffle levels ----
    {
        const int sub = lane & 3, rr = lane >> 2;
        #pragma unroll
        for (int p = 0; p < 2; ++p) {
            const int row = w * 32 + p * 16 + rr;
            ushort4 raw[4];
            #pragma unroll
            for (int q = 0; q < 4; ++q) raw[q] = *(const ushort4*)&x2[row][sub * 16 + q * 4];
            float xv[16];
            #pragma unroll
            for (int q = 0; q < 4; ++q) {
                xv[q * 4 + 0] = bf2f(raw[q].x);
                xv[q * 4 + 1] = bf2f(raw[q].y);
                xv[q * 4 + 2] = bf2f(raw[q].z);
                xv[q * 4 + 3] = bf2f(raw[q].w);
            }
            float s = 0.f, s2 = 0.f;
            #pragma unroll
            for (int e = 0; e < 16; ++e) { s += xv[e]; s2 += xv[e] * xv[e]; }
            s += __shfl_xor(s, 1);  s2 += __shfl_xor(s2, 1);
            s += __shfl_xor(s, 2);  s2 += __shfl_xor(s2, 2);
            float m = s * 0.015625f;
            float var = s2 * 0.015625f - m * m;
            float rstd = rsqrtf(var + 1e-5f);
            #pragma unroll
            for (int q = 0; q < 4; ++q) {
                float4 lg4 = ((const float4*)lno_g)[sub * 4 + q];
                float4 lb4 = ((const float4*)lno_b)[sub * 4 + q];
                ushort4 zw;
                zw.x = f2bf((xv[q * 4 + 0] - m) * rstd * lg4.x + lb4.x);
                zw.y = f2bf((xv[q * 4 + 1] - m) * rstd * lg4.y + lb4.y);
                zw.z = f2bf((xv[q * 4 + 2] - m) * rstd * lg4.z + lb4.z);
                zw.w = f2bf((xv[q * 4 + 3] - m) * rstd * lg4.w + lb4.w);
                *(ushort4*)&x2[row][sub * 16 + q * 4] = zw;
            }
        }
    }
    __syncthreads();

    unsigned short* o_lds = &x1[0][0];   // [128][64]
    const int rsel = lane & 15, koff = lane >> 4;
    #pragma unroll
    for (int mh = 0; mh < 2; ++mh) {
        const int mi = 2 * w + mh;
        bf16x8 a0 = *(const bf16x8*)&x2[mi * 16 + rsel][koff * 8];
        bf16x8 a1 = *(const bf16x8*)&x2[mi * 16 + rsel][32 + koff * 8];
        #pragma unroll
        for (int n = 0; n < 4; ++n) {
            f32x4 pacc = {0.f, 0.f, 0.f, 0.f};
            const unsigned short* wrow = WoutB + (size_t)(n * 16 + rsel) * 64;
            pacc = MFMA16(a0, *(const bf16x8*)&wrow[koff * 8], pacc);
            pacc = MFMA16(a1, *(const bf16x8*)&wrow[32 + koff * 8], pacc);
            const float bo = bout[n * 16 + rsel];
            #pragma unroll
            for (int r = 0; r < 4; ++r)
                o_lds[(mi * 16 + koff * 4 + r) * 64 + n * 16 + rsel] = f2bf(pacc[r] + bo);
        }
    }
    __syncthreads();

    #pragma unroll
    for (int q = 0; q < 4; ++q) {
        int e = q * 2048 + t * 8;
        int c = e >> 6, o = e & 63;
        size_t pos = (size_t)(bb * LL + irow) * LL + c0 + c;
        uint4 ov = *(const uint4*)&o_lds[c * 64 + o];
        uint4 gv = *(const uint4*)&G[pos * DD + o];
        const unsigned short* ovp = (const unsigned short*)&ov;
        const unsigned short* gvp = (const unsigned short*)&gv;
        float4 p0 = *(const float4*)&pairIn[pos * DD + o];
        float4 p1 = *(const float4*)&pairIn[pos * DD + o + 4];
        float4 r0, r1;
        r0.x = p0.x + bf2f(ovp[0]) * bf2f(gvp[0]);
        r0.y = p0.y + bf2f(ovp[1]) * bf2f(gvp[1]);
        r0.z = p0.z + bf2f(ovp[2]) * bf2f(gvp[2]);
        r0.w = p0.w + bf2f(ovp[3]) * bf2f(gvp[3]);
        r1.x = p1.x + bf2f(ovp[4]) * bf2f(gvp[4]);
        r1.y = p1.y + bf2f(ovp[5]) * bf2f(gvp[5]);
        r1.z = p1.z + bf2f(ovp[6]) * bf2f(gvp[6]);
        r1.w = p1.w + bf2f(ovp[7]) * bf2f(gvp[7]);
        *(float4*)&out[pos * DD + o] = r0;
        *(float4*)&out[pos * DD + o + 4] = r1;
    }
}

// ----------------------------------------------------------------- launch ---
extern "C" void kernel_launch(void* const* d_in, const int* in_sizes, int n_in,
                              void* d_out, int out_size, void* d_ws, size_t ws_size,
                              hipStream_t stream) {
    const float* pair    = (const float*)d_in[0];
    const float* torsion = (const float*)d_in[1];
    const float* ln_g    = (const float*)d_in[2];
    const float* ln_b    = (const float*)d_in[3];
    const float* Wl      = (const float*)d_in[4];
    const float* Wr      = (const float*)d_in[5];
    const float* Wlg     = (const float*)d_in[6];
    const float* blg     = (const float*)d_in[7];
    const float* Wrg     = (const float*)d_in[8];
    const float* brg     = (const float*)d_in[9];
    const float* Wog     = (const float*)d_in[10];
    const float* bog     = (const float*)d_in[11];
    const float* Wout    = (const float*)d_in[12];
    const float* bout    = (const float*)d_in[13];
    const float* lno_g   = (const float*)d_in[14];
    const float* lno_b   = (const float*)d_in[15];
    const float* Wt      = (const float*)d_in[16];
    const float* bt      = (const float*)d_in[17];
    float* outp = (float*)d_out;

    const size_t PLANE_B = (size_t)128 * LL * LL * 2;   // 64 MiB per block
    const size_t need = 4 * PLANE_B + (320 * 64 + 64 * 64) * 2;
    if (ws_size < need) return;

    char* ws = (char*)d_ws;
    unsigned short* At    = (unsigned short*)(ws);
    unsigned short* Bt_   = (unsigned short*)(ws + PLANE_B);
    unsigned short* G     = (unsigned short*)(ws + 2 * PLANE_B);
    unsigned short* Xt    = (unsigned short*)(ws + 3 * PLANE_B);
    unsigned short* Wcat  = (unsigned short*)(ws + 4 * PLANE_B);
    unsigned short* WoutB = Wcat + 320 * 64;

    prep_w<<<dim3(40), dim3(256), 0, stream>>>(Wl, Wr, Wlg, Wrg, Wog, Wout, Wcat, WoutB);
    k1_proj<<<dim3(4, LL, 2), dim3(256), 0, stream>>>(pair, torsion, ln_g, ln_b, blg, brg,
                                                      bog, Wt, bt, Wcat, At, Bt_, G);
    k2_gemm<<<dim3(16, 128), dim3(256), 0, stream>>>(At, Bt_, Xt);
    k3_out<<<dim3(4, LL, 2), dim3(256), 0, stream>>>(Xt, G, pair, WoutB, lno_g, lno_b, bout, outp);
}

// Round 7
// 261.011 us; speedup vs baseline: 2.0954x; 1.0866x over previous
//
#include <hip/hip_runtime.h>
#include <stdint.h>

#define LL 512
#define DD 64

typedef __attribute__((ext_vector_type(8))) short bf16x8;
typedef __attribute__((ext_vector_type(4))) float f32x4;

#define MFMA16(a, b, c) __builtin_amdgcn_mfma_f32_16x16x32_bf16((a), (b), (c), 0, 0, 0)

__device__ __forceinline__ float bf2f(unsigned short u) {
    union { unsigned int i; float f; } v; v.i = ((unsigned int)u) << 16; return v.f;
}
__device__ __forceinline__ unsigned short f2bf(float f) {
    union { float f; unsigned int i; } v; v.f = f;
    unsigned int i = v.i;
    return (unsigned short)((i + 0x7FFFu + ((i >> 16) & 1u)) >> 16);  // RNE
}
// Newton-refined rcp sigmoid: validated (absmax identical to exact division).
// Raw rcpf without refinement is banned (round-3 regression).
__device__ __forceinline__ float sigm(float x) {
    float d = 1.0f + __expf(-x);
    float y = __builtin_amdgcn_rcpf(d);
    return y * __builtin_fmaf(-d, y, 2.0f);
}

// ---------------------------------------------------------------- prep ------
__global__ void prep_w(const float* __restrict__ Wl, const float* __restrict__ Wr,
                       const float* __restrict__ Wlg, const float* __restrict__ Wrg,
                       const float* __restrict__ Wog, const float* __restrict__ Wout,
                       unsigned short* __restrict__ Wcat, unsigned short* __restrict__ WoutB) {
    int t = threadIdx.x + blockIdx.x * blockDim.x;
    int stride = blockDim.x * gridDim.x;
    for (int idx = t; idx < 320 * 64; idx += stride) {
        int row = idx >> 6, col = idx & 63;
        int sec = row >> 6, r = row & 63;
        float v;
        switch (sec) {
            case 0:  v = Wl[r * 64 + col];  break;
            case 1:  v = Wlg[r * 64 + col]; break;
            case 2:  v = Wr[r * 64 + col];  break;
            case 3:  v = Wrg[r * 64 + col]; break;
            default: v = Wog[r * 64 + col]; break;
        }
        Wcat[idx] = f2bf(v);
    }
    for (int idx = t; idx < 64 * 64; idx += stride) WoutB[idx] = f2bf(Wout[idx]);
}

// ------------------------------------------------- k1: LN + proj + gates ----
// (unchanged from round 6 -- validated at absmax 0.125)
__launch_bounds__(256)
__global__ void k1_proj(const float* __restrict__ pair, const float* __restrict__ torsion,
                        const float* __restrict__ ln_g, const float* __restrict__ ln_b,
                        const float* __restrict__ blg, const float* __restrict__ brg,
                        const float* __restrict__ bog, const float* __restrict__ Wt,
                        const float* __restrict__ bt, const unsigned short* __restrict__ Wcat,
                        unsigned short* __restrict__ At, unsigned short* __restrict__ Bt,
                        unsigned short* __restrict__ G) {
    const int bb = blockIdx.z, irow = blockIdx.y, c0 = blockIdx.x * 128;
    const int t = threadIdx.x, w = t >> 6, lane = t & 63;
    const int rsel = lane & 15, koff = lane >> 4;
    const int col = w * 16 + rsel;            // this wave's output channel
    __shared__ unsigned short zs[128][72];    // z bf16 [pos][d]; later reused for G
    __shared__ unsigned short awL[64][132];   // aw d-major [d][pos]
    __shared__ unsigned short bL[64][132];    // b  d-major [d][pos]

    float tww;
    {
        float acc = bt[0];
        #pragma unroll
        for (int n = 0; n < 6; ++n) acc += torsion[(bb * LL + irow) * 6 + n] * Wt[n];
        tww = sigm(acc);
    }

    // Hoisted weight fragments: 5 matrices x 2 k-halves, 16B each (40 VGPR).
    bf16x8 wfr[5][2];
    #pragma unroll
    for (int s = 0; s < 5; ++s)
        #pragma unroll
        for (int kh = 0; kh < 2; ++kh)
            wfr[s][kh] = *(const bf16x8*)&Wcat[(size_t)(s * 64 + col) * 64 + kh * 32 + koff * 8];
    const float vblg = blg[col], vbrg = brg[col], vbog = bog[col];

    // ---- LN: 4 lanes per row, 16 elems/lane in registers, 2 shuffle levels --
    {
        const int sub = lane & 3, rr = lane >> 2;
        const float4* pr4 = (const float4*)(pair + ((size_t)(bb * LL + irow) * LL + c0) * DD);
        #pragma unroll
        for (int p = 0; p < 2; ++p) {
            const int row = w * 32 + p * 16 + rr;
            float4 x[4];
            #pragma unroll
            for (int q = 0; q < 4; ++q) x[q] = pr4[row * 16 + sub * 4 + q];
            float s = 0.f, s2 = 0.f;
            #pragma unroll
            for (int q = 0; q < 4; ++q) {
                s += x[q].x + x[q].y + x[q].z + x[q].w;
                s2 += x[q].x * x[q].x + x[q].y * x[q].y + x[q].z * x[q].z + x[q].w * x[q].w;
            }
            s += __shfl_xor(s, 1);  s2 += __shfl_xor(s2, 1);
            s += __shfl_xor(s, 2);  s2 += __shfl_xor(s2, 2);
            float m = s * 0.015625f;
            float var = s2 * 0.015625f - m * m;
            float rstd = rsqrtf(var + 1e-5f);
            #pragma unroll
            for (int q = 0; q < 4; ++q) {
                float4 lg4 = ((const float4*)ln_g)[sub * 4 + q];
                float4 lb4 = ((const float4*)ln_b)[sub * 4 + q];
                ushort4 zw;
                zw.x = f2bf((x[q].x - m) * rstd * lg4.x + lb4.x);
                zw.y = f2bf((x[q].y - m) * rstd * lg4.y + lb4.y);
                zw.z = f2bf((x[q].z - m) * rstd * lg4.z + lb4.z);
                zw.w = f2bf((x[q].w - m) * rstd * lg4.w + lb4.w);
                *(ushort4*)&zs[row][sub * 16 + q * 4] = zw;
            }
        }
    }
    __syncthreads();

    // ---- projections: 8 position tiles, weights stay in registers ----
    ushort4 gk[8];
    #pragma unroll
    for (int mi = 0; mi < 8; ++mi) {
        bf16x8 a0 = *(const bf16x8*)&zs[mi * 16 + rsel][koff * 8];
        bf16x8 a1 = *(const bf16x8*)&zs[mi * 16 + rsel][32 + koff * 8];
        f32x4 pl = {0.f, 0.f, 0.f, 0.f}, plg = pl, pr = pl, prg = pl, pog = pl;
        pl  = MFMA16(a0, wfr[0][0], pl);  pl  = MFMA16(a1, wfr[0][1], pl);
        plg = MFMA16(a0, wfr[1][0], plg); plg = MFMA16(a1, wfr[1][1], plg);
        pr  = MFMA16(a0, wfr[2][0], pr);  pr  = MFMA16(a1, wfr[2][1], pr);
        prg = MFMA16(a0, wfr[3][0], prg); prg = MFMA16(a1, wfr[3][1], prg);
        pog = MFMA16(a0, wfr[4][0], pog); pog = MFMA16(a1, wfr[4][1], pog);

        const int crow = mi * 16 + koff * 4;
        unsigned short aw4[4], bm4[4], g4[4];
        #pragma unroll
        for (int r = 0; r < 4; ++r) {
            float av = pl[r] * sigm(plg[r] + vblg) * tww;
            float bv = pr[r] * sigm(prg[r] + vbrg);
            float gv = sigm(pog[r] + vbog);
            aw4[r] = f2bf(av); bm4[r] = f2bf(bv); g4[r] = f2bf(gv);
        }
        *(ushort4*)&awL[col][crow] = make_ushort4(aw4[0], aw4[1], aw4[2], aw4[3]);
        *(ushort4*)&bL[col][crow]  = make_ushort4(bm4[0], bm4[1], bm4[2], bm4[3]);
        gk[mi] = make_ushort4(g4[0], g4[1], g4[2], g4[3]);
    }
    __syncthreads();   // all waves done reading z from zs

    // Dump gate regs into zs (wave-private cells), [pos][d] == G layout.
    #pragma unroll
    for (int mi = 0; mi < 8; ++mi) {
        const int rbase = mi * 16 + koff * 4;
        zs[rbase + 0][col] = gk[mi].x;
        zs[rbase + 1][col] = gk[mi].y;
        zs[rbase + 2][col] = gk[mi].z;
        zs[rbase + 3][col] = gk[mi].w;
    }
    __syncthreads();

    // Tail: all global stores fire-and-forget (no barrier after this point).
    #pragma unroll
    for (int it = 0; it < 8; ++it) {
        int d = it * 8 + (t >> 5);
        int c8 = (t & 31) * 4;
        size_t base = ((size_t)(bb * 64 + d) * LL + irow) * LL + c0 + c8;
        *(ushort4*)&At[base] = *(const ushort4*)&awL[d][c8];
        *(ushort4*)&Bt[base] = *(const ushort4*)&bL[d][c8];
    }
    #pragma unroll
    for (int it = 0; it < 8; ++it) {
        int r = it * 16 + (t >> 4), cc = (t & 15) * 4;
        size_t pos = (size_t)(bb * LL + irow) * LL + c0 + r;
        *(ushort4*)&G[pos * DD + cc] = *(const ushort4*)&zs[r][cc];
    }
}

// ------------------------------------------ k2: batched plane GEMM (AB^T) ---
// Round-7 redesign (was: 14.9M LDS bank conflicts, 70KB LDS -> 2 blocks/CU,
// MfmaUtil 11%):
//  * Fragment-linear LDS: per-lane pre-permuted GLOBAL source so each K-step
//    subtile sits in LDS in exact MFMA fragment order. ds_write AND ds_read
//    are base + lane*16 -> linear -> zero bank conflicts by construction.
//    (Global coalescing unchanged: per load instr, 4 lanes (koff 0-3) cover a
//    contiguous 64B row segment; 16 rows x 64B = same transactions as before.)
//  * Double-buffered A/B (4 x 8KB) union'd with Cs (34.8KB): LDS 70->35KB ->
//    4 blocks/CU; 1 barrier per K-step (was 2).
// Arithmetic identical to round-6 k2 (same fragments, same MFMA order).
union K2Sh {
    unsigned short ab[4][4096];   // [A0,B0,A1,B1][8 subtiles * 512 shorts]
    unsigned short cs[128][136];  // output staging, pitch 272B
};

__launch_bounds__(256, 4)
__global__ void k2_gemm(const unsigned short* __restrict__ At,
                        const unsigned short* __restrict__ Bt,
                        unsigned short* __restrict__ Xt) {
    int lin = blockIdx.x + (blockIdx.y << 4);          // 2048 blocks
    int nlin = (lin & 7) * 256 + (lin >> 3);           // bijective XCD chunking
    const int p = nlin >> 4;
    const int tile = nlin & 15;
    const int i0 = (tile >> 2) * 128, j0 = (tile & 3) * 128;
    const unsigned short* Ap = At + (size_t)p * LL * LL + (size_t)i0 * LL;
    const unsigned short* Bp = Bt + (size_t)p * LL * LL + (size_t)j0 * LL;
    __shared__ K2Sh sh;
    const int t = threadIdx.x, lane = t & 63, w = t >> 6;
    const int wm = w >> 1, wn = w & 1;

    f32x4 acc[4][4];
    #pragma unroll
    for (int i = 0; i < 4; ++i)
        #pragma unroll
        for (int j = 0; j < 4; ++j) acc[i][j] = (f32x4){0.f, 0.f, 0.f, 0.f};

    // Staging assignment: thread t stages fragment-lane (t&63) of subtiles
    // s = w + 4q (q=0,1). Global element for subtile s, lane l:
    //   row = s*16 + (l&15), col = k0 + (l>>4)*8   (8 shorts = 16B)
    const unsigned short* apq[2];
    const unsigned short* bpq[2];
    #pragma unroll
    for (int q = 0; q < 2; ++q) {
        const int s = w + 4 * q;
        const int grow = s * 16 + (lane & 15);
        const int gcol = (lane >> 4) * 8;
        apq[q] = Ap + (size_t)grow * LL + gcol;
        bpq[q] = Bp + (size_t)grow * LL + gcol;
    }
    const int wofs = w * 512 + lane * 8;   // LDS write offset (shorts), +q*2048

    // Prologue: stage K-step 0 into buffer 0.
    uint4 ra[2], rb[2];
    #pragma unroll
    for (int q = 0; q < 2; ++q) {
        ra[q] = *(const uint4*)apq[q];
        rb[q] = *(const uint4*)bpq[q];
    }
    #pragma unroll
    for (int q = 0; q < 2; ++q) {
        *(uint4*)&sh.ab[0][wofs + q * 2048] = ra[q];
        *(uint4*)&sh.ab[1][wofs + q * 2048] = rb[q];
    }
    __syncthreads();

    for (int k = 0; k < 16; ++k) {
        const int cur = k & 1;
        // Issue next K-step's global loads first (latency hides under MFMA).
        if (k < 15) {
            #pragma unroll
            for (int q = 0; q < 2; ++q) {
                apq[q] += 32; bpq[q] += 32;
                ra[q] = *(const uint4*)apq[q];
                rb[q] = *(const uint4*)bpq[q];
            }
        }
        const unsigned short* As = sh.ab[cur * 2];
        const unsigned short* Bs = sh.ab[cur * 2 + 1];
        bf16x8 af[4], bfr[4];
        #pragma unroll
        for (int mi = 0; mi < 4; ++mi)
            af[mi] = *(const bf16x8*)&As[(wm * 4 + mi) * 512 + lane * 8];
        #pragma unroll
        for (int ni = 0; ni < 4; ++ni)
            bfr[ni] = *(const bf16x8*)&Bs[(wn * 4 + ni) * 512 + lane * 8];
        #pragma unroll
        for (int mi = 0; mi < 4; ++mi)
            #pragma unroll
            for (int ni = 0; ni < 4; ++ni)
                acc[mi][ni] = MFMA16(af[mi], bfr[ni], acc[mi][ni]);
        if (k < 15) {
            unsigned short* An = sh.ab[(cur ^ 1) * 2];
            unsigned short* Bn = sh.ab[(cur ^ 1) * 2 + 1];
            #pragma unroll
            for (int q = 0; q < 2; ++q) {
                *(uint4*)&An[wofs + q * 2048] = ra[q];
                *(uint4*)&Bn[wofs + q * 2048] = rb[q];
            }
        }
        __syncthreads();
    }

    // Epilogue: stage C through the (now free) LDS union, coalesced store.
    const int rsel = lane & 15, koff = lane >> 4;
    const float s = 1.0f / (sqrtf((float)LL) + 1e-8f);
    #pragma unroll
    for (int mi = 0; mi < 4; ++mi)
        #pragma unroll
        for (int ni = 0; ni < 4; ++ni)
            #pragma unroll
            for (int r = 0; r < 4; ++r)
                sh.cs[wm * 64 + mi * 16 + koff * 4 + r][wn * 64 + ni * 16 + rsel] =
                    f2bf(acc[mi][ni][r] * s);
    __syncthreads();
    #pragma unroll
    for (int it = 0; it < 8; ++it) {
        int row = it * 16 + (t >> 4), colc = (t & 15) * 8;
        uint4 v = *(const uint4*)&sh.cs[row][colc];
        *(uint4*)&Xt[((size_t)p * LL + i0 + row) * LL + j0 + colc] = v;
    }
}

// ----------------------------- k3: transpose + LN + out-proj + gate + res ---
// (unchanged from round 6)
__launch_bounds__(256)
__global__ void k3_out(const unsigned short* __restrict__ Xt, const unsigned short* __restrict__ G,
                       const float* __restrict__ pairIn, const unsigned short* __restrict__ WoutB,
                       const float* __restrict__ lno_g, const float* __restrict__ lno_b,
                       const float* __restrict__ bout, float* __restrict__ out) {
    const int bb = blockIdx.z, irow = blockIdx.y, c0 = blockIdx.x * 128;
    const int t = threadIdx.x, w = t >> 6, lane = t & 63;
    __shared__ unsigned short x1[64][128];   // [d][c] staging, reused as o_lds [128][64]
    __shared__ unsigned short x2[128][72];   // [c][d] transposed

    #pragma unroll
    for (int q = 0; q < 4; ++q) {
        int idx = t + q * 256, d = idx >> 4, c8 = idx & 15;
        uint4 v = *(const uint4*)&Xt[((size_t)(bb * 64 + d) * LL + irow) * LL + c0 + c8 * 8];
        *(uint4*)&x1[d][c8 * 8] = v;
    }
    __syncthreads();
    {
        const int c = t & 127, half = t >> 7;
        unsigned short tmp[32];
        #pragma unroll
        for (int dd = 0; dd < 32; ++dd) tmp[dd] = x1[half * 32 + dd][c];
        #pragma unroll
        for (int q = 0; q < 4; ++q)
            *(uint4*)&x2[c][half * 32 + q * 8] = *(const uint4*)&tmp[q * 8];
    }
    __syncthreads();

    // ---- LN: 4 lanes per row, 16 elems/lane, 2 shuffle levels ----
    {
        const int sub = lane & 3, rr = lane >> 2;
        #pragma unroll
        for (int p = 0; p < 2; ++p) {
            const int row = w * 32 + p * 16 + rr;
            ushort4 raw[4];
            #pragma unroll
            for (int q = 0; q < 4; ++q) raw[q] = *(const ushort4*)&x2[row][sub * 16 + q * 4];
            float xv[16];
            #pragma unroll
            for (int q = 0; q < 4; ++q) {
                xv[q * 4 + 0] = bf2f(raw[q].x);
                xv[q * 4 + 1] = bf2f(raw[q].y);
                xv[q * 4 + 2] = bf2f(raw[q].z);
                xv[q * 4 + 3] = bf2f(raw[q].w);
            }
            float s = 0.f, s2 = 0.f;
            #pragma unroll
            for (int e = 0; e < 16; ++e) { s += xv[e]; s2 += xv[e] * xv[e]; }
            s += __shfl_xor(s, 1);  s2 += __shfl_xor(s2, 1);
            s += __shfl_xor(s, 2);  s2 += __shfl_xor(s2, 2);
            float m = s * 0.015625f;
            float var = s2 * 0.015625f - m * m;
            float rstd = rsqrtf(var + 1e-5f);
            #pragma unroll
            for (int q = 0; q < 4; ++q) {
                float4 lg4 = ((const float4*)lno_g)[sub * 4 + q];
                float4 lb4 = ((const float4*)lno_b)[sub * 4 + q];
                ushort4 zw;
                zw.x = f2bf((xv[q * 4 + 0] - m) * rstd * lg4.x + lb4.x);
                zw.y = f2bf((xv[q * 4 + 1] - m) * rstd * lg4.y + lb4.y);
                zw.z = f2bf((xv[q * 4 + 2] - m) * rstd * lg4.z + lb4.z);
                zw.w = f2bf((xv[q * 4 + 3] - m) * rstd * lg4.w + lb4.w);
                *(ushort4*)&x2[row][sub * 16 + q * 4] = zw;
            }
        }
    }
    __syncthreads();

    unsigned short* o_lds = &x1[0][0];   // [128][64]
    const int rsel = lane & 15, koff = lane >> 4;
    #pragma unroll
    for (int mh = 0; mh < 2; ++mh) {
        const int mi = 2 * w + mh;
        bf16x8 a0 = *(const bf16x8*)&x2[mi * 16 + rsel][koff * 8];
        bf16x8 a1 = *(const bf16x8*)&x2[mi * 16 + rsel][32 + koff * 8];
        #pragma unroll
        for (int n = 0; n < 4; ++n) {
            f32x4 pacc = {0.f, 0.f, 0.f, 0.f};
            const unsigned short* wrow = WoutB + (size_t)(n * 16 + rsel) * 64;
            pacc = MFMA16(a0, *(const bf16x8*)&wrow[koff * 8], pacc);
            pacc = MFMA16(a1, *(const bf16x8*)&wrow[32 + koff * 8], pacc);
            const float bo = bout[n * 16 + rsel];
            #pragma unroll
            for (int r = 0; r < 4; ++r)
                o_lds[(mi * 16 + koff * 4 + r) * 64 + n * 16 + rsel] = f2bf(pacc[r] + bo);
        }
    }
    __syncthreads();

    #pragma unroll
    for (int q = 0; q < 4; ++q) {
        int e = q * 2048 + t * 8;
        int c = e >> 6, o = e & 63;
        size_t pos = (size_t)(bb * LL + irow) * LL + c0 + c;
        uint4 ov = *(const uint4*)&o_lds[c * 64 + o];
        uint4 gv = *(const uint4*)&G[pos * DD + o];
        const unsigned short* ovp = (const unsigned short*)&ov;
        const unsigned short* gvp = (const unsigned short*)&gv;
        float4 p0 = *(const float4*)&pairIn[pos * DD + o];
        float4 p1 = *(const float4*)&pairIn[pos * DD + o + 4];
        float4 r0, r1;
        r0.x = p0.x + bf2f(ovp[0]) * bf2f(gvp[0]);
        r0.y = p0.y + bf2f(ovp[1]) * bf2f(gvp[1]);
        r0.z = p0.z + bf2f(ovp[2]) * bf2f(gvp[2]);
        r0.w = p0.w + bf2f(ovp[3]) * bf2f(gvp[3]);
        r1.x = p1.x + bf2f(ovp[4]) * bf2f(gvp[4]);
        r1.y = p1.y + bf2f(ovp[5]) * bf2f(gvp[5]);
        r1.z = p1.z + bf2f(ovp[6]) * bf2f(gvp[6]);
        r1.w = p1.w + bf2f(ovp[7]) * bf2f(gvp[7]);
        *(float4*)&out[pos * DD + o] = r0;
        *(float4*)&out[pos * DD + o + 4] = r1;
    }
}

// ----------------------------------------------------------------- launch ---
extern "C" void kernel_launch(void* const* d_in, const int* in_sizes, int n_in,
                              void* d_out, int out_size, void* d_ws, size_t ws_size,
                              hipStream_t stream) {
    const float* pair    = (const float*)d_in[0];
    const float* torsion = (const float*)d_in[1];
    const float* ln_g    = (const float*)d_in[2];
    const float* ln_b    = (const float*)d_in[3];
    const float* Wl      = (const float*)d_in[4];
    const float* Wr      = (const float*)d_in[5];
    const float* Wlg     = (const float*)d_in[6];
    const float* blg     = (const float*)d_in[7];
    const float* Wrg     = (const float*)d_in[8];
    const float* brg     = (const float*)d_in[9];
    const float* Wog     = (const float*)d_in[10];
    const float* bog     = (const float*)d_in[11];
    const float* Wout    = (const float*)d_in[12];
    const float* bout    = (const float*)d_in[13];
    const float* lno_g   = (const float*)d_in[14];
    const float* lno_b   = (const float*)d_in[15];
    const float* Wt      = (const float*)d_in[16];
    const float* bt      = (const float*)d_in[17];
    float* outp = (float*)d_out;

    const size_t PLANE_B = (size_t)128 * LL * LL * 2;   // 64 MiB per block
    const size_t need = 4 * PLANE_B + (320 * 64 + 64 * 64) * 2;
    if (ws_size < need) return;

    char* ws = (char*)d_ws;
    unsigned short* At    = (unsigned short*)(ws);
    unsigned short* Bt_   = (unsigned short*)(ws + PLANE_B);
    unsigned short* G     = (unsigned short*)(ws + 2 * PLANE_B);
    unsigned short* Xt    = (unsigned short*)(ws + 3 * PLANE_B);
    unsigned short* Wcat  = (unsigned short*)(ws + 4 * PLANE_B);
    unsigned short* WoutB = Wcat + 320 * 64;

    prep_w<<<dim3(40), dim3(256), 0, stream>>>(Wl, Wr, Wlg, Wrg, Wog, Wout, Wcat, WoutB);
    k1_proj<<<dim3(4, LL, 2), dim3(256), 0, stream>>>(pair, torsion, ln_g, ln_b, blg, brg,
                                                      bog, Wt, bt, Wcat, At, Bt_, G);
    k2_gemm<<<dim3(16, 128), dim3(256), 0, stream>>>(At, Bt_, Xt);
    k3_out<<<dim3(4, LL, 2), dim3(256), 0, stream>>>(Xt, G, pair, WoutB, lno_g, lno_b, bout, outp);
}

// Round 8
// 259.553 us; speedup vs baseline: 2.1071x; 1.0056x over previous
//
#include <hip/hip_runtime.h>
#include <stdint.h>

#define LL 512
#define DD 64

typedef __attribute__((ext_vector_type(8))) short bf16x8;
typedef __attribute__((ext_vector_type(4))) float f32x4;

#define MFMA16(a, b, c) __builtin_amdgcn_mfma_f32_16x16x32_bf16((a), (b), (c), 0, 0, 0)

__device__ __forceinline__ float bf2f(unsigned short u) {
    union { unsigned int i; float f; } v; v.i = ((unsigned int)u) << 16; return v.f;
}
__device__ __forceinline__ unsigned short f2bf(float f) {
    union { float f; unsigned int i; } v; v.f = f;
    unsigned int i = v.i;
    return (unsigned short)((i + 0x7FFFu + ((i >> 16) & 1u)) >> 16);  // RNE
}
// Newton-refined rcp sigmoid: validated (absmax identical to exact division).
// Raw rcpf without refinement is banned (round-3 regression).
__device__ __forceinline__ float sigm(float x) {
    float d = 1.0f + __expf(-x);
    float y = __builtin_amdgcn_rcpf(d);
    return y * __builtin_fmaf(-d, y, 2.0f);
}

// Direct global->LDS DMA, 16B per lane. LDS dest is wave-uniform base +
// lane*16 (hardware-defined); global src is per-lane.
__device__ __forceinline__ void gload_lds16(const unsigned short* g, unsigned short* l) {
    __builtin_amdgcn_global_load_lds(
        (const __attribute__((address_space(1))) void*)g,
        (__attribute__((address_space(3))) void*)l, 16, 0, 0);
}

// ---------------------------------------------------------------- prep ------
__global__ void prep_w(const float* __restrict__ Wl, const float* __restrict__ Wr,
                       const float* __restrict__ Wlg, const float* __restrict__ Wrg,
                       const float* __restrict__ Wog, const float* __restrict__ Wout,
                       unsigned short* __restrict__ Wcat, unsigned short* __restrict__ WoutB) {
    int t = threadIdx.x + blockIdx.x * blockDim.x;
    int stride = blockDim.x * gridDim.x;
    for (int idx = t; idx < 320 * 64; idx += stride) {
        int row = idx >> 6, col = idx & 63;
        int sec = row >> 6, r = row & 63;
        float v;
        switch (sec) {
            case 0:  v = Wl[r * 64 + col];  break;
            case 1:  v = Wlg[r * 64 + col]; break;
            case 2:  v = Wr[r * 64 + col];  break;
            case 3:  v = Wrg[r * 64 + col]; break;
            default: v = Wog[r * 64 + col]; break;
        }
        Wcat[idx] = f2bf(v);
    }
    for (int idx = t; idx < 64 * 64; idx += stride) WoutB[idx] = f2bf(Wout[idx]);
}

// ------------------------------------------------- k1: LN + proj + gates ----
// (unchanged from round 6 -- validated)
__launch_bounds__(256)
__global__ void k1_proj(const float* __restrict__ pair, const float* __restrict__ torsion,
                        const float* __restrict__ ln_g, const float* __restrict__ ln_b,
                        const float* __restrict__ blg, const float* __restrict__ brg,
                        const float* __restrict__ bog, const float* __restrict__ Wt,
                        const float* __restrict__ bt, const unsigned short* __restrict__ Wcat,
                        unsigned short* __restrict__ At, unsigned short* __restrict__ Bt,
                        unsigned short* __restrict__ G) {
    const int bb = blockIdx.z, irow = blockIdx.y, c0 = blockIdx.x * 128;
    const int t = threadIdx.x, w = t >> 6, lane = t & 63;
    const int rsel = lane & 15, koff = lane >> 4;
    const int col = w * 16 + rsel;            // this wave's output channel
    __shared__ unsigned short zs[128][72];    // z bf16 [pos][d]; later reused for G
    __shared__ unsigned short awL[64][132];   // aw d-major [d][pos]
    __shared__ unsigned short bL[64][132];    // b  d-major [d][pos]

    float tww;
    {
        float acc = bt[0];
        #pragma unroll
        for (int n = 0; n < 6; ++n) acc += torsion[(bb * LL + irow) * 6 + n] * Wt[n];
        tww = sigm(acc);
    }

    // Hoisted weight fragments: 5 matrices x 2 k-halves, 16B each (40 VGPR).
    bf16x8 wfr[5][2];
    #pragma unroll
    for (int s = 0; s < 5; ++s)
        #pragma unroll
        for (int kh = 0; kh < 2; ++kh)
            wfr[s][kh] = *(const bf16x8*)&Wcat[(size_t)(s * 64 + col) * 64 + kh * 32 + koff * 8];
    const float vblg = blg[col], vbrg = brg[col], vbog = bog[col];

    // ---- LN: 4 lanes per row, 16 elems/lane in registers, 2 shuffle levels --
    {
        const int sub = lane & 3, rr = lane >> 2;
        const float4* pr4 = (const float4*)(pair + ((size_t)(bb * LL + irow) * LL + c0) * DD);
        #pragma unroll
        for (int p = 0; p < 2; ++p) {
            const int row = w * 32 + p * 16 + rr;
            float4 x[4];
            #pragma unroll
            for (int q = 0; q < 4; ++q) x[q] = pr4[row * 16 + sub * 4 + q];
            float s = 0.f, s2 = 0.f;
            #pragma unroll
            for (int q = 0; q < 4; ++q) {
                s += x[q].x + x[q].y + x[q].z + x[q].w;
                s2 += x[q].x * x[q].x + x[q].y * x[q].y + x[q].z * x[q].z + x[q].w * x[q].w;
            }
            s += __shfl_xor(s, 1);  s2 += __shfl_xor(s2, 1);
            s += __shfl_xor(s, 2);  s2 += __shfl_xor(s2, 2);
            float m = s * 0.015625f;
            float var = s2 * 0.015625f - m * m;
            float rstd = rsqrtf(var + 1e-5f);
            #pragma unroll
            for (int q = 0; q < 4; ++q) {
                float4 lg4 = ((const float4*)ln_g)[sub * 4 + q];
                float4 lb4 = ((const float4*)ln_b)[sub * 4 + q];
                ushort4 zw;
                zw.x = f2bf((x[q].x - m) * rstd * lg4.x + lb4.x);
                zw.y = f2bf((x[q].y - m) * rstd * lg4.y + lb4.y);
                zw.z = f2bf((x[q].z - m) * rstd * lg4.z + lb4.z);
                zw.w = f2bf((x[q].w - m) * rstd * lg4.w + lb4.w);
                *(ushort4*)&zs[row][sub * 16 + q * 4] = zw;
            }
        }
    }
    __syncthreads();

    // ---- projections: 8 position tiles, weights stay in registers ----
    ushort4 gk[8];
    #pragma unroll
    for (int mi = 0; mi < 8; ++mi) {
        bf16x8 a0 = *(const bf16x8*)&zs[mi * 16 + rsel][koff * 8];
        bf16x8 a1 = *(const bf16x8*)&zs[mi * 16 + rsel][32 + koff * 8];
        f32x4 pl = {0.f, 0.f, 0.f, 0.f}, plg = pl, pr = pl, prg = pl, pog = pl;
        pl  = MFMA16(a0, wfr[0][0], pl);  pl  = MFMA16(a1, wfr[0][1], pl);
        plg = MFMA16(a0, wfr[1][0], plg); plg = MFMA16(a1, wfr[1][1], plg);
        pr  = MFMA16(a0, wfr[2][0], pr);  pr  = MFMA16(a1, wfr[2][1], pr);
        prg = MFMA16(a0, wfr[3][0], prg); prg = MFMA16(a1, wfr[3][1], prg);
        pog = MFMA16(a0, wfr[4][0], pog); pog = MFMA16(a1, wfr[4][1], pog);

        const int crow = mi * 16 + koff * 4;
        unsigned short aw4[4], bm4[4], g4[4];
        #pragma unroll
        for (int r = 0; r < 4; ++r) {
            float av = pl[r] * sigm(plg[r] + vblg) * tww;
            float bv = pr[r] * sigm(prg[r] + vbrg);
            float gv = sigm(pog[r] + vbog);
            aw4[r] = f2bf(av); bm4[r] = f2bf(bv); g4[r] = f2bf(gv);
        }
        *(ushort4*)&awL[col][crow] = make_ushort4(aw4[0], aw4[1], aw4[2], aw4[3]);
        *(ushort4*)&bL[col][crow]  = make_ushort4(bm4[0], bm4[1], bm4[2], bm4[3]);
        gk[mi] = make_ushort4(g4[0], g4[1], g4[2], g4[3]);
    }
    __syncthreads();   // all waves done reading z from zs

    // Dump gate regs into zs (wave-private cells), [pos][d] == G layout.
    #pragma unroll
    for (int mi = 0; mi < 8; ++mi) {
        const int rbase = mi * 16 + koff * 4;
        zs[rbase + 0][col] = gk[mi].x;
        zs[rbase + 1][col] = gk[mi].y;
        zs[rbase + 2][col] = gk[mi].z;
        zs[rbase + 3][col] = gk[mi].w;
    }
    __syncthreads();

    // Tail: all global stores fire-and-forget (no barrier after this point).
    #pragma unroll
    for (int it = 0; it < 8; ++it) {
        int d = it * 8 + (t >> 5);
        int c8 = (t & 31) * 4;
        size_t base = ((size_t)(bb * 64 + d) * LL + irow) * LL + c0 + c8;
        *(ushort4*)&At[base] = *(const ushort4*)&awL[d][c8];
        *(ushort4*)&Bt[base] = *(const ushort4*)&bL[d][c8];
    }
    #pragma unroll
    for (int it = 0; it < 8; ++it) {
        int r = it * 16 + (t >> 4), cc = (t & 15) * 4;
        size_t pos = (size_t)(bb * LL + irow) * LL + c0 + r;
        *(ushort4*)&G[pos * DD + cc] = *(const ushort4*)&zs[r][cc];
    }
}

// ------------------------------------------ k2: batched plane GEMM (AB^T) ---
// Round-8: staging switched from reg round-trip (global->VGPR->ds_write, which
// serialized vmcnt(0) into every K-step; MfmaUtil 13.8%) to direct
// global_load_lds width=16 (m97 structure). LDS dest is wave-uniform base +
// lane*16 == our fragment-linear layout; global src is the per-lane permuted
// address (HK pre-swizzled-source pattern). Prefetch for step k+1 issues at
// the top of step k and only drains at the barrier.
union K2Sh {
    unsigned short ab[4][4096];   // [A0,B0,A1,B1][8 subtiles * 512 shorts]
    unsigned short cs[128][136];  // output staging, pitch 272B
};

__launch_bounds__(256, 4)
__global__ void k2_gemm(const unsigned short* __restrict__ At,
                        const unsigned short* __restrict__ Bt,
                        unsigned short* __restrict__ Xt) {
    int lin = blockIdx.x + (blockIdx.y << 4);          // 2048 blocks
    int nlin = (lin & 7) * 256 + (lin >> 3);           // bijective XCD chunking
    const int p = nlin >> 4;
    const int tile = nlin & 15;
    const int i0 = (tile >> 2) * 128, j0 = (tile & 3) * 128;
    const unsigned short* Ap = At + (size_t)p * LL * LL + (size_t)i0 * LL;
    const unsigned short* Bp = Bt + (size_t)p * LL * LL + (size_t)j0 * LL;
    __shared__ K2Sh sh;
    const int t = threadIdx.x, lane = t & 63, w = t >> 6;
    const int wm = w >> 1, wn = w & 1;

    f32x4 acc[4][4];
    #pragma unroll
    for (int i = 0; i < 4; ++i)
        #pragma unroll
        for (int j = 0; j < 4; ++j) acc[i][j] = (f32x4){0.f, 0.f, 0.f, 0.f};

    // Per-lane permuted global source: subtile s = w + 4q, lane l covers
    // row = s*16 + (l&15), col = k0 + (l>>4)*8. LDS dest (wave-uniform):
    // &ab[buf][w*512 + q*2048], lane l lands at +l*16B = fragment order.
    const unsigned short* apq[2];
    const unsigned short* bpq[2];
    #pragma unroll
    for (int q = 0; q < 2; ++q) {
        const int s = w + 4 * q;
        const int grow = s * 16 + (lane & 15);
        const int gcol = (lane >> 4) * 8;
        apq[q] = Ap + (size_t)grow * LL + gcol;
        bpq[q] = Bp + (size_t)grow * LL + gcol;
    }
    const int wbase = w * 512;   // uniform LDS offset (shorts), +q*2048

    // Prologue: stage K-step 0 into buffer 0.
    #pragma unroll
    for (int q = 0; q < 2; ++q) {
        gload_lds16(apq[q], &sh.ab[0][wbase + q * 2048]);
        gload_lds16(bpq[q], &sh.ab[1][wbase + q * 2048]);
    }
    __syncthreads();

    for (int k = 0; k < 16; ++k) {
        const int cur = k & 1;
        // Issue next K-step's DMA first; it drains at this step's barrier.
        if (k < 15) {
            #pragma unroll
            for (int q = 0; q < 2; ++q) {
                apq[q] += 32; bpq[q] += 32;
                gload_lds16(apq[q], &sh.ab[(cur ^ 1) * 2][wbase + q * 2048]);
                gload_lds16(bpq[q], &sh.ab[(cur ^ 1) * 2 + 1][wbase + q * 2048]);
            }
        }
        const unsigned short* As = sh.ab[cur * 2];
        const unsigned short* Bs = sh.ab[cur * 2 + 1];
        bf16x8 af[4], bfr[4];
        #pragma unroll
        for (int mi = 0; mi < 4; ++mi)
            af[mi] = *(const bf16x8*)&As[(wm * 4 + mi) * 512 + lane * 8];
        #pragma unroll
        for (int ni = 0; ni < 4; ++ni)
            bfr[ni] = *(const bf16x8*)&Bs[(wn * 4 + ni) * 512 + lane * 8];
        #pragma unroll
        for (int mi = 0; mi < 4; ++mi)
            #pragma unroll
            for (int ni = 0; ni < 4; ++ni)
                acc[mi][ni] = MFMA16(af[mi], bfr[ni], acc[mi][ni]);
        __syncthreads();
    }

    // Epilogue: stage C through the (now free) LDS union, coalesced store.
    const int rsel = lane & 15, koff = lane >> 4;
    const float s = 1.0f / (sqrtf((float)LL) + 1e-8f);
    #pragma unroll
    for (int mi = 0; mi < 4; ++mi)
        #pragma unroll
        for (int ni = 0; ni < 4; ++ni)
            #pragma unroll
            for (int r = 0; r < 4; ++r)
                sh.cs[wm * 64 + mi * 16 + koff * 4 + r][wn * 64 + ni * 16 + rsel] =
                    f2bf(acc[mi][ni][r] * s);
    __syncthreads();
    #pragma unroll
    for (int it = 0; it < 8; ++it) {
        int row = it * 16 + (t >> 4), colc = (t & 15) * 8;
        uint4 v = *(const uint4*)&sh.cs[row][colc];
        *(uint4*)&Xt[((size_t)p * LL + i0 + row) * LL + j0 + colc] = v;
    }
}

// ----------------------------- k3: transpose + LN + out-proj + gate + res ---
// (unchanged from round 6)
__launch_bounds__(256)
__global__ void k3_out(const unsigned short* __restrict__ Xt, const unsigned short* __restrict__ G,
                       const float* __restrict__ pairIn, const unsigned short* __restrict__ WoutB,
                       const float* __restrict__ lno_g, const float* __restrict__ lno_b,
                       const float* __restrict__ bout, float* __restrict__ out) {
    const int bb = blockIdx.z, irow = blockIdx.y, c0 = blockIdx.x * 128;
    const int t = threadIdx.x, w = t >> 6, lane = t & 63;
    __shared__ unsigned short x1[64][128];   // [d][c] staging, reused as o_lds [128][64]
    __shared__ unsigned short x2[128][72];   // [c][d] transposed

    #pragma unroll
    for (int q = 0; q < 4; ++q) {
        int idx = t + q * 256, d = idx >> 4, c8 = idx & 15;
        uint4 v = *(const uint4*)&Xt[((size_t)(bb * 64 + d) * LL + irow) * LL + c0 + c8 * 8];
        *(uint4*)&x1[d][c8 * 8] = v;
    }
    __syncthreads();
    {
        const int c = t & 127, half = t >> 7;
        unsigned short tmp[32];
        #pragma unroll
        for (int dd = 0; dd < 32; ++dd) tmp[dd] = x1[half * 32 + dd][c];
        #pragma unroll
        for (int q = 0; q < 4; ++q)
            *(uint4*)&x2[c][half * 32 + q * 8] = *(const uint4*)&tmp[q * 8];
    }
    __syncthreads();

    // ---- LN: 4 lanes per row, 16 elems/lane, 2 shuffle levels ----
    {
        const int sub = lane & 3, rr = lane >> 2;
        #pragma unroll
        for (int p = 0; p < 2; ++p) {
            const int row = w * 32 + p * 16 + rr;
            ushort4 raw[4];
            #pragma unroll
            for (int q = 0; q < 4; ++q) raw[q] = *(const ushort4*)&x2[row][sub * 16 + q * 4];
            float xv[16];
            #pragma unroll
            for (int q = 0; q < 4; ++q) {
                xv[q * 4 + 0] = bf2f(raw[q].x);
                xv[q * 4 + 1] = bf2f(raw[q].y);
                xv[q * 4 + 2] = bf2f(raw[q].z);
                xv[q * 4 + 3] = bf2f(raw[q].w);
            }
            float s = 0.f, s2 = 0.f;
            #pragma unroll
            for (int e = 0; e < 16; ++e) { s += xv[e]; s2 += xv[e] * xv[e]; }
            s += __shfl_xor(s, 1);  s2 += __shfl_xor(s2, 1);
            s += __shfl_xor(s, 2);  s2 += __shfl_xor(s2, 2);
            float m = s * 0.015625f;
            float var = s2 * 0.015625f - m * m;
            float rstd = rsqrtf(var + 1e-5f);
            #pragma unroll
            for (int q = 0; q < 4; ++q) {
                float4 lg4 = ((const float4*)lno_g)[sub * 4 + q];
                float4 lb4 = ((const float4*)lno_b)[sub * 4 + q];
                ushort4 zw;
                zw.x = f2bf((xv[q * 4 + 0] - m) * rstd * lg4.x + lb4.x);
                zw.y = f2bf((xv[q * 4 + 1] - m) * rstd * lg4.y + lb4.y);
                zw.z = f2bf((xv[q * 4 + 2] - m) * rstd * lg4.z + lb4.z);
                zw.w = f2bf((xv[q * 4 + 3] - m) * rstd * lg4.w + lb4.w);
                *(ushort4*)&x2[row][sub * 16 + q * 4] = zw;
            }
        }
    }
    __syncthreads();

    unsigned short* o_lds = &x1[0][0];   // [128][64]
    const int rsel = lane & 15, koff = lane >> 4;
    #pragma unroll
    for (int mh = 0; mh < 2; ++mh) {
        const int mi = 2 * w + mh;
        bf16x8 a0 = *(const bf16x8*)&x2[mi * 16 + rsel][koff * 8];
        bf16x8 a1 = *(const bf16x8*)&x2[mi * 16 + rsel][32 + koff * 8];
        #pragma unroll
        for (int n = 0; n < 4; ++n) {
            f32x4 pacc = {0.f, 0.f, 0.f, 0.f};
            const unsigned short* wrow = WoutB + (size_t)(n * 16 + rsel) * 64;
            pacc = MFMA16(a0, *(const bf16x8*)&wrow[koff * 8], pacc);
            pacc = MFMA16(a1, *(const bf16x8*)&wrow[32 + koff * 8], pacc);
            const float bo = bout[n * 16 + rsel];
            #pragma unroll
            for (int r = 0; r < 4; ++r)
                o_lds[(mi * 16 + koff * 4 + r) * 64 + n * 16 + rsel] = f2bf(pacc[r] + bo);
        }
    }
    __syncthreads();

    #pragma unroll
    for (int q = 0; q < 4; ++q) {
        int e = q * 2048 + t * 8;
        int c = e >> 6, o = e & 63;
        size_t pos = (size_t)(bb * LL + irow) * LL + c0 + c;
        uint4 ov = *(const uint4*)&o_lds[c * 64 + o];
        uint4 gv = *(const uint4*)&G[pos * DD + o];
        const unsigned short* ovp = (const unsigned short*)&ov;
        const unsigned short* gvp = (const unsigned short*)&gv;
        float4 p0 = *(const float4*)&pairIn[pos * DD + o];
        float4 p1 = *(const float4*)&pairIn[pos * DD + o + 4];
        float4 r0, r1;
        r0.x = p0.x + bf2f(ovp[0]) * bf2f(gvp[0]);
        r0.y = p0.y + bf2f(ovp[1]) * bf2f(gvp[1]);
        r0.z = p0.z + bf2f(ovp[2]) * bf2f(gvp[2]);
        r0.w = p0.w + bf2f(ovp[3]) * bf2f(gvp[3]);
        r1.x = p1.x + bf2f(ovp[4]) * bf2f(gvp[4]);
        r1.y = p1.y + bf2f(ovp[5]) * bf2f(gvp[5]);
        r1.z = p1.z + bf2f(ovp[6]) * bf2f(gvp[6]);
        r1.w = p1.w + bf2f(ovp[7]) * bf2f(gvp[7]);
        *(float4*)&out[pos * DD + o] = r0;
        *(float4*)&out[pos * DD + o + 4] = r1;
    }
}

// ----------------------------------------------------------------- launch ---
extern "C" void kernel_launch(void* const* d_in, const int* in_sizes, int n_in,
                              void* d_out, int out_size, void* d_ws, size_t ws_size,
                              hipStream_t stream) {
    const float* pair    = (const float*)d_in[0];
    const float* torsion = (const float*)d_in[1];
    const float* ln_g    = (const float*)d_in[2];
    const float* ln_b    = (const float*)d_in[3];
    const float* Wl      = (const float*)d_in[4];
    const float* Wr      = (const float*)d_in[5];
    const float* Wlg     = (const float*)d_in[6];
    const float* blg     = (const float*)d_in[7];
    const float* Wrg     = (const float*)d_in[8];
    const float* brg     = (const float*)d_in[9];
    const float* Wog     = (const float*)d_in[10];
    const float* bog     = (const float*)d_in[11];
    const float* Wout    = (const float*)d_in[12];
    const float* bout    = (const float*)d_in[13];
    const float* lno_g   = (const float*)d_in[14];
    const float* lno_b   = (const float*)d_in[15];
    const float* Wt      = (const float*)d_in[16];
    const float* bt      = (const float*)d_in[17];
    float* outp = (float*)d_out;

    const size_t PLANE_B = (size_t)128 * LL * LL * 2;   // 64 MiB per block
    const size_t need = 4 * PLANE_B + (320 * 64 + 64 * 64) * 2;
    if (ws_size < need) return;

    char* ws = (char*)d_ws;
    unsigned short* At    = (unsigned short*)(ws);
    unsigned short* Bt_   = (unsigned short*)(ws + PLANE_B);
    unsigned short* G     = (unsigned short*)(ws + 2 * PLANE_B);
    unsigned short* Xt    = (unsigned short*)(ws + 3 * PLANE_B);
    unsigned short* Wcat  = (unsigned short*)(ws + 4 * PLANE_B);
    unsigned short* WoutB = Wcat + 320 * 64;

    prep_w<<<dim3(40), dim3(256), 0, stream>>>(Wl, Wr, Wlg, Wrg, Wog, Wout, Wcat, WoutB);
    k1_proj<<<dim3(4, LL, 2), dim3(256), 0, stream>>>(pair, torsion, ln_g, ln_b, blg, brg,
                                                      bog, Wt, bt, Wcat, At, Bt_, G);
    k2_gemm<<<dim3(16, 128), dim3(256), 0, stream>>>(At, Bt_, Xt);
    k3_out<<<dim3(4, LL, 2), dim3(256), 0, stream>>>(Xt, G, pair, WoutB, lno_g, lno_b, bout, outp);
}